// Round 1
// baseline (1719.415 us; speedup 1.0000x reference)
//
#include <hip/hip_runtime.h>

#define HH 4  // heads

__device__ __forceinline__ unsigned fenc(float v){
    unsigned u = __float_as_uint(v);
    return (u >> 31) ? ~u : (u | 0x80000000u);
}
__device__ __forceinline__ float fdec(unsigned e){
    unsigned u = (e >> 31) ? (e ^ 0x80000000u) : ~e;
    return __uint_as_float(u);
}
__device__ __forceinline__ float lrelu(float v){ return v > 0.f ? v : 0.2f*v; }

// h = X @ W  (W is [IC, 4*C] row-major), plus per-head attention logits
// block = 4*C threads (64 or 256), one node per block
template<int C>
__global__ void gemm_gat(const float* __restrict__ X, const float* __restrict__ W,
                         const float* __restrict__ a_s, const float* __restrict__ a_d,
                         float* __restrict__ h, float* __restrict__ als, float* __restrict__ ald,
                         int IC) {
    const int OC = 4*C;
    int n = blockIdx.x;
    int t = threadIdx.x;
    __shared__ float xs[128];
    for (int k = t; k < IC; k += OC) xs[k] = X[(size_t)n*IC + k];
    __syncthreads();
    float acc = 0.f;
    for (int k = 0; k < IC; ++k) acc += xs[k] * W[k*OC + t];
    h[(size_t)n*OC + t] = acc;
    int hh = t / C, c = t % C;
    float ps = acc * a_s[hh*C + c];
    float pd = acc * a_d[hh*C + c];
    #pragma unroll
    for (int m = 1; m < C; m <<= 1) { ps += __shfl_xor(ps, m); pd += __shfl_xor(pd, m); }
    if (c == 0) { als[n*HH + hh] = ps; ald[n*HH + hh] = pd; }
}

// self-loop initializes the running max
__global__ void init_max(const float* __restrict__ als, const float* __restrict__ ald,
                         unsigned* __restrict__ menc, int N){
    int i = blockIdx.x*blockDim.x + threadIdx.x;  // over N*HH
    if (i < N*HH) {
        float v = lrelu(als[i] + ald[i]);   // self edge: src == dst
        menc[i] = fenc(v);
    }
}

__global__ void edge_max(const int* __restrict__ ei, const float* __restrict__ als,
                         const float* __restrict__ ald, unsigned* __restrict__ menc, int E){
    int i = blockIdx.x*blockDim.x + threadIdx.x;  // over E*HH
    if (i < E*HH) {
        int e = i / HH, hh = i % HH;
        int s = ei[e], d = ei[E + e];
        float v = lrelu(als[s*HH + hh] + ald[d*HH + hh]);
        atomicMax(&menc[d*HH + hh], fenc(v));
    }
}

// self-loop initializes den and agg
template<int C>
__global__ void init_den_agg(const float* __restrict__ als, const float* __restrict__ ald,
                             const unsigned* __restrict__ menc, const float* __restrict__ h,
                             float* __restrict__ den, float* __restrict__ agg, int N){
    int i = blockIdx.x*blockDim.x + threadIdx.x;  // over N*HH*C
    if (i < N*HH*C) {
        int c = i % C; int nh = i / C;            // nh = n*HH + hh
        float v = lrelu(als[nh] + ald[nh]);
        float ex = expf(v - fdec(menc[nh]));
        if (c == 0) den[nh] = ex;
        agg[i] = ex * h[i];
    }
}

template<int C>
__global__ void edge_agg(const int* __restrict__ ei, const float* __restrict__ als,
                         const float* __restrict__ ald, const unsigned* __restrict__ menc,
                         const float* __restrict__ h, float* __restrict__ den,
                         float* __restrict__ agg, int E){
    const int GRP = 4*C;            // threads per edge (64 or 256)
    const int PER = 256/GRP;        // edges per block
    int r = threadIdx.x % GRP;
    int e = blockIdx.x*PER + threadIdx.x/GRP;
    if (e >= E) return;
    int hh = r / C, c = r % C;
    int s = ei[e], d = ei[E + e];
    float v = lrelu(als[s*HH + hh] + ald[d*HH + hh]);
    float ex = expf(v - fdec(menc[d*HH + hh]));
    if (c == 0) atomicAdd(&den[d*HH + hh], ex);
    atomicAdd(&agg[((size_t)d*HH + hh)*C + c], ex * h[((size_t)s*HH + hh)*C + c]);
}

// layers 1/2: concat heads, +bias, BN, ELU
__global__ void finalize_cat(const float* __restrict__ agg, const float* __restrict__ den,
                             const float* __restrict__ b, const float* __restrict__ g,
                             const float* __restrict__ bb, const float* __restrict__ bm,
                             const float* __restrict__ bv, float* __restrict__ out, int N){
    int i = blockIdx.x*blockDim.x + threadIdx.x;  // N*64
    if (i < N*64) {
        int n = i / 64, oc = i % 64; int hh = oc / 16;
        float val = agg[i] / den[n*HH + hh] + b[oc];
        val = g[oc]*(val - bm[oc])*rsqrtf(bv[oc] + 1e-5f) + bb[oc];
        out[i] = val > 0.f ? val : expm1f(val);
    }
}

// layer 3: mean over heads, +bias, BN (no ELU)
__global__ void finalize_mean(const float* __restrict__ agg, const float* __restrict__ den,
                              const float* __restrict__ b, const float* __restrict__ g,
                              const float* __restrict__ bb, const float* __restrict__ bm,
                              const float* __restrict__ bv, float* __restrict__ out, int N){
    int i = blockIdx.x*blockDim.x + threadIdx.x;  // N*64
    if (i < N*64) {
        int n = i / 64, c = i % 64;
        float s = 0.f;
        #pragma unroll
        for (int hh = 0; hh < 4; ++hh)
            s += agg[((size_t)n*4 + hh)*64 + c] / den[n*4 + hh];
        float val = 0.25f*s + b[c];
        out[i] = g[c]*(val - bm[c])*rsqrtf(bv[c] + 1e-5f) + bb[c];
    }
}

__global__ void classifier(const float* __restrict__ hin, const float* __restrict__ cW1,
                           const float* __restrict__ cb1, const float* __restrict__ cW2,
                           const float* __restrict__ cb2, float* __restrict__ out, int N){
    __shared__ float w1[64*32];
    __shared__ float b1s[32], w2[32];
    int t = threadIdx.x;
    for (int k = t; k < 64*32; k += 256) w1[k] = cW1[k];
    if (t < 32) { b1s[t] = cb1[t]; w2[t] = cW2[t]; }
    __syncthreads();
    int n = blockIdx.x*256 + t;
    if (n >= N) return;
    float hrow[64];
    #pragma unroll
    for (int k = 0; k < 64; ++k) hrow[k] = hin[(size_t)n*64 + k];
    float acc2 = cb2[0];
    #pragma unroll 4
    for (int j = 0; j < 32; ++j) {
        float a = b1s[j];
        #pragma unroll
        for (int k = 0; k < 64; ++k) a += hrow[k]*w1[k*32 + j];
        float e = a > 0.f ? a : expm1f(a);
        acc2 += e * w2[j];
    }
    out[n] = acc2;
}

extern "C" void kernel_launch(void* const* d_in, const int* in_sizes, int n_in,
                              void* d_out, int out_size, void* d_ws, size_t ws_size,
                              hipStream_t stream) {
    const float* x    = (const float*)d_in[0];
    const int*   ei   = (const int*)  d_in[1];
    const float* W1   = (const float*)d_in[2];
    const float* a1s  = (const float*)d_in[3];
    const float* a1d  = (const float*)d_in[4];
    const float* b1   = (const float*)d_in[5];
    const float* W2   = (const float*)d_in[6];
    const float* a2s  = (const float*)d_in[7];
    const float* a2d  = (const float*)d_in[8];
    const float* b2   = (const float*)d_in[9];
    const float* W3   = (const float*)d_in[10];
    const float* a3s  = (const float*)d_in[11];
    const float* a3d  = (const float*)d_in[12];
    const float* b3   = (const float*)d_in[13];
    const float* bn1g = (const float*)d_in[14];
    const float* bn1b = (const float*)d_in[15];
    const float* bn1m = (const float*)d_in[16];
    const float* bn1v = (const float*)d_in[17];
    const float* bn2g = (const float*)d_in[18];
    const float* bn2b = (const float*)d_in[19];
    const float* bn2m = (const float*)d_in[20];
    const float* bn2v = (const float*)d_in[21];
    const float* bn3g = (const float*)d_in[22];
    const float* bn3b = (const float*)d_in[23];
    const float* bn3m = (const float*)d_in[24];
    const float* bn3v = (const float*)d_in[25];
    const float* cW1  = (const float*)d_in[26];
    const float* cb1  = (const float*)d_in[27];
    const float* cW2  = (const float*)d_in[28];
    const float* cb2  = (const float*)d_in[29];

    const int N = in_sizes[0] / 128;
    const int E = in_sizes[1] / 2;

    // workspace layout (fp32): h[N*256] agg[N*256] als[N*4] ald[N*4] menc[N*4] den[N*4] hin[N*64]
    float*    h    = (float*)d_ws;
    float*    agg  = h   + (size_t)N*256;
    float*    als  = agg + (size_t)N*256;
    float*    ald  = als + (size_t)N*4;
    unsigned* menc = (unsigned*)(ald + (size_t)N*4);
    float*    den  = (float*)(menc + (size_t)N*4);
    float*    hin  = den + (size_t)N*4;

    const int B = 256;
    int gNH   = (N*4   + B-1)/B;
    int gEH   = (E*4   + B-1)/B;
    int gN64  = (N*64  + B-1)/B;
    int gN256 = (N*256 + B-1)/B;

    // ---- layer 1 (IC=128, C=16, concat) ----
    gemm_gat<16><<<N, 64, 0, stream>>>(x, W1, a1s, a1d, h, als, ald, 128);
    init_max<<<gNH, B, 0, stream>>>(als, ald, menc, N);
    edge_max<<<gEH, B, 0, stream>>>(ei, als, ald, menc, E);
    init_den_agg<16><<<gN64, B, 0, stream>>>(als, ald, menc, h, den, agg, N);
    edge_agg<16><<<(E + 3)/4, B, 0, stream>>>(ei, als, ald, menc, h, den, agg, E);
    finalize_cat<<<gN64, B, 0, stream>>>(agg, den, b1, bn1g, bn1b, bn1m, bn1v, hin, N);

    // ---- layer 2 (IC=64, C=16, concat) ----
    gemm_gat<16><<<N, 64, 0, stream>>>(hin, W2, a2s, a2d, h, als, ald, 64);
    init_max<<<gNH, B, 0, stream>>>(als, ald, menc, N);
    edge_max<<<gEH, B, 0, stream>>>(ei, als, ald, menc, E);
    init_den_agg<16><<<gN64, B, 0, stream>>>(als, ald, menc, h, den, agg, N);
    edge_agg<16><<<(E + 3)/4, B, 0, stream>>>(ei, als, ald, menc, h, den, agg, E);
    finalize_cat<<<gN64, B, 0, stream>>>(agg, den, b2, bn2g, bn2b, bn2m, bn2v, hin, N);

    // ---- layer 3 (IC=64, C=64, mean) ----
    gemm_gat<64><<<N, 256, 0, stream>>>(hin, W3, a3s, a3d, h, als, ald, 64);
    init_max<<<gNH, B, 0, stream>>>(als, ald, menc, N);
    edge_max<<<gEH, B, 0, stream>>>(ei, als, ald, menc, E);
    init_den_agg<64><<<gN256, B, 0, stream>>>(als, ald, menc, h, den, agg, N);
    edge_agg<64><<<E, B, 0, stream>>>(ei, als, ald, menc, h, den, agg, E);
    finalize_mean<<<gN64, B, 0, stream>>>(agg, den, b3, bn3g, bn3b, bn3m, bn3v, hin, N);

    // ---- classifier ----
    classifier<<<(N + B-1)/B, B, 0, stream>>>(hin, cW1, cb1, cW2, cb2, (float*)d_out, N);
}

// Round 2
// 941.898 us; speedup vs baseline: 1.8255x; 1.8255x over previous
//
#include <hip/hip_runtime.h>

#define HH 4  // heads

__device__ __forceinline__ float lrelu(float v){ return v > 0.f ? v : 0.2f*v; }

// h = X @ W  (W is [IC, 4*C] row-major), plus per-head attention logits
// block = 4*C threads (64 or 256), one node per block
template<int C>
__global__ void gemm_gat(const float* __restrict__ X, const float* __restrict__ W,
                         const float* __restrict__ a_s, const float* __restrict__ a_d,
                         float* __restrict__ h, float* __restrict__ als, float* __restrict__ ald,
                         int IC) {
    const int OC = 4*C;
    int n = blockIdx.x;
    int t = threadIdx.x;
    __shared__ float xs[128];
    for (int k = t; k < IC; k += OC) xs[k] = X[(size_t)n*IC + k];
    __syncthreads();
    float acc = 0.f;
    for (int k = 0; k < IC; ++k) acc += xs[k] * W[k*OC + t];
    h[(size_t)n*OC + t] = acc;
    int hh = t / C, c = t % C;
    float ps = acc * a_s[hh*C + c];
    float pd = acc * a_d[hh*C + c];
    #pragma unroll
    for (int m = 1; m < C; m <<= 1) { ps += __shfl_xor(ps, m); pd += __shfl_xor(pd, m); }
    if (c == 0) { als[n*HH + hh] = ps; ald[n*HH + hh] = pd; }
}

// ---------------- CSR build (per launch; graph is identical every call) ----------------

__global__ void zero_i32(int* __restrict__ p, int n){
    int i = blockIdx.x*256 + threadIdx.x;
    if (i < n) p[i] = 0;
}

__global__ void count_deg(const int* __restrict__ ei, int* __restrict__ deg, int E){
    int e = blockIdx.x*256 + threadIdx.x;
    if (e < E) atomicAdd(&deg[ei[E + e]], 1);
}

// single block, 1024 threads: chunked exclusive scan of deg[0..N) -> row_off, cursor
__global__ void scan_deg(const int* __restrict__ deg, int* __restrict__ row_off,
                         int* __restrict__ cursor, int N){
    __shared__ int part[1024];
    int t = threadIdx.x;
    int chunk = (N + 1023) >> 10;
    int beg = t*chunk;
    int end = min(beg + chunk, N);
    int s = 0;
    for (int i = beg; i < end; ++i) s += deg[i];
    part[t] = s;
    __syncthreads();
    for (int off = 1; off < 1024; off <<= 1){
        int u = (t >= off) ? part[t - off] : 0;
        __syncthreads();
        part[t] += u;
        __syncthreads();
    }
    int o = part[t] - s;   // exclusive prefix
    for (int i = beg; i < end; ++i){
        row_off[i] = o; cursor[i] = o; o += deg[i];
    }
    if (t == 1023) row_off[N] = part[1023];
}

__global__ void fill_csr(const int* __restrict__ ei, int* __restrict__ cursor,
                         int* __restrict__ ssrc, int E){
    int e = blockIdx.x*256 + threadIdx.x;
    if (e < E){
        int d = ei[E + e];
        int p = atomicAdd(&cursor[d], 1);
        ssrc[p] = ei[e];
    }
}

// ---------------- fused segment-softmax + aggregate + bias + BN + ELU ----------------

// concat layers (C=16, OC=64): 4 nodes per 256-block, one wave per node, no syncs
__global__ void gat_agg16(const int* __restrict__ row_off, const int* __restrict__ ssrc,
                          const float* __restrict__ als, const float* __restrict__ ald,
                          const float* __restrict__ h, const float* __restrict__ b,
                          const float* __restrict__ g, const float* __restrict__ bb,
                          const float* __restrict__ bm, const float* __restrict__ bv,
                          float* __restrict__ out, int N){
    int lane = threadIdx.x & 63;
    int n = blockIdx.x*4 + (threadIdx.x >> 6);
    if (n >= N) return;
    int hh = lane >> 4;
    float ad = ald[n*HH + hh];
    float vself = lrelu(als[n*HH + hh] + ad);
    int beg = row_off[n], end = row_off[n+1];
    float m = vself;
    for (int i = beg; i < end; ++i)
        m = fmaxf(m, lrelu(als[ssrc[i]*HH + hh] + ad));
    float den = __expf(vself - m);
    float acc = den * h[(size_t)n*64 + lane];
    for (int i = beg; i < end; ++i){
        int s = ssrc[i];
        float ex = __expf(lrelu(als[s*HH + hh] + ad) - m);
        den += ex;
        acc += ex * h[(size_t)s*64 + lane];
    }
    float val = acc/den + b[lane];
    val = g[lane]*(val - bm[lane])*rsqrtf(bv[lane] + 1e-5f) + bb[lane];
    out[(size_t)n*64 + lane] = val > 0.f ? val : expm1f(val);
}

// layer 3 (C=64, OC=256): one node per 256-block, mean over heads, BN, no ELU
__global__ void gat_agg64(const int* __restrict__ row_off, const int* __restrict__ ssrc,
                          const float* __restrict__ als, const float* __restrict__ ald,
                          const float* __restrict__ h, const float* __restrict__ b,
                          const float* __restrict__ g, const float* __restrict__ bb,
                          const float* __restrict__ bm, const float* __restrict__ bv,
                          float* __restrict__ out, int N){
    int t = threadIdx.x;
    int n = blockIdx.x;
    int hh = t >> 6;
    float ad = ald[n*HH + hh];
    float vself = lrelu(als[n*HH + hh] + ad);
    int beg = row_off[n], end = row_off[n+1];
    float m = vself;
    for (int i = beg; i < end; ++i)
        m = fmaxf(m, lrelu(als[ssrc[i]*HH + hh] + ad));
    float den = __expf(vself - m);
    float acc = den * h[(size_t)n*256 + t];
    for (int i = beg; i < end; ++i){
        int s = ssrc[i];
        float ex = __expf(lrelu(als[s*HH + hh] + ad) - m);
        den += ex;
        acc += ex * h[(size_t)s*256 + t];
    }
    __shared__ float red[256];
    red[t] = acc/den;
    __syncthreads();
    if (t < 64){
        float s = red[t] + red[64+t] + red[128+t] + red[192+t];
        float val = 0.25f*s + b[t];
        out[(size_t)n*64 + t] = g[t]*(val - bm[t])*rsqrtf(bv[t] + 1e-5f) + bb[t];
    }
}

__global__ void classifier(const float* __restrict__ hin, const float* __restrict__ cW1,
                           const float* __restrict__ cb1, const float* __restrict__ cW2,
                           const float* __restrict__ cb2, float* __restrict__ out, int N){
    __shared__ float w1[64*32];
    __shared__ float b1s[32], w2[32];
    int t = threadIdx.x;
    for (int k = t; k < 64*32; k += 256) w1[k] = cW1[k];
    if (t < 32) { b1s[t] = cb1[t]; w2[t] = cW2[t]; }
    __syncthreads();
    int n = blockIdx.x*256 + t;
    if (n >= N) return;
    float hrow[64];
    #pragma unroll
    for (int k = 0; k < 64; ++k) hrow[k] = hin[(size_t)n*64 + k];
    float acc2 = cb2[0];
    #pragma unroll 4
    for (int j = 0; j < 32; ++j) {
        float a = b1s[j];
        #pragma unroll
        for (int k = 0; k < 64; ++k) a += hrow[k]*w1[k*32 + j];
        float e = a > 0.f ? a : expm1f(a);
        acc2 += e * w2[j];
    }
    out[n] = acc2;
}

extern "C" void kernel_launch(void* const* d_in, const int* in_sizes, int n_in,
                              void* d_out, int out_size, void* d_ws, size_t ws_size,
                              hipStream_t stream) {
    const float* x    = (const float*)d_in[0];
    const int*   ei   = (const int*)  d_in[1];
    const float* W1   = (const float*)d_in[2];
    const float* a1s  = (const float*)d_in[3];
    const float* a1d  = (const float*)d_in[4];
    const float* b1   = (const float*)d_in[5];
    const float* W2   = (const float*)d_in[6];
    const float* a2s  = (const float*)d_in[7];
    const float* a2d  = (const float*)d_in[8];
    const float* b2   = (const float*)d_in[9];
    const float* W3   = (const float*)d_in[10];
    const float* a3s  = (const float*)d_in[11];
    const float* a3d  = (const float*)d_in[12];
    const float* b3   = (const float*)d_in[13];
    const float* bn1g = (const float*)d_in[14];
    const float* bn1b = (const float*)d_in[15];
    const float* bn1m = (const float*)d_in[16];
    const float* bn1v = (const float*)d_in[17];
    const float* bn2g = (const float*)d_in[18];
    const float* bn2b = (const float*)d_in[19];
    const float* bn2m = (const float*)d_in[20];
    const float* bn2v = (const float*)d_in[21];
    const float* bn3g = (const float*)d_in[22];
    const float* bn3b = (const float*)d_in[23];
    const float* bn3m = (const float*)d_in[24];
    const float* bn3v = (const float*)d_in[25];
    const float* cW1  = (const float*)d_in[26];
    const float* cb1  = (const float*)d_in[27];
    const float* cW2  = (const float*)d_in[28];
    const float* cb2  = (const float*)d_in[29];

    const int N = in_sizes[0] / 128;
    const int E = in_sizes[1] / 2;

    // workspace: h[N*256] als[N*4] ald[N*4] hin[N*64] | deg[N] row_off[N+1] cursor[N] ssrc[E]
    float* h   = (float*)d_ws;
    float* als = h   + (size_t)N*256;
    float* ald = als + (size_t)N*4;
    float* hin = ald + (size_t)N*4;
    int* deg     = (int*)(hin + (size_t)N*64);
    int* row_off = deg + N;
    int* cursor  = row_off + (N + 1);
    int* ssrc    = cursor + N;

    const int B = 256;
    int gN  = (N + B-1)/B;
    int gE  = (E + B-1)/B;

    // ---- CSR build (dst-grouped src lists), reused by all 3 layers ----
    zero_i32<<<gN, B, 0, stream>>>(deg, N);
    count_deg<<<gE, B, 0, stream>>>(ei, deg, E);
    scan_deg<<<1, 1024, 0, stream>>>(deg, row_off, cursor, N);
    fill_csr<<<gE, B, 0, stream>>>(ei, cursor, ssrc, E);

    // ---- layer 1 (IC=128, C=16, concat) ----
    gemm_gat<16><<<N, 64, 0, stream>>>(x, W1, a1s, a1d, h, als, ald, 128);
    gat_agg16<<<(N + 3)/4, B, 0, stream>>>(row_off, ssrc, als, ald, h, b1,
                                           bn1g, bn1b, bn1m, bn1v, hin, N);

    // ---- layer 2 (IC=64, C=16, concat) ----
    gemm_gat<16><<<N, 64, 0, stream>>>(hin, W2, a2s, a2d, h, als, ald, 64);
    gat_agg16<<<(N + 3)/4, B, 0, stream>>>(row_off, ssrc, als, ald, h, b2,
                                           bn2g, bn2b, bn2m, bn2v, hin, N);

    // ---- layer 3 (IC=64, C=64, mean) ----
    gemm_gat<64><<<N, 256, 0, stream>>>(hin, W3, a3s, a3d, h, als, ald, 64);
    gat_agg64<<<N, B, 0, stream>>>(row_off, ssrc, als, ald, h, b3,
                                   bn3g, bn3b, bn3m, bn3v, hin, N);

    // ---- classifier ----
    classifier<<<gN, B, 0, stream>>>(hin, cW1, cb1, cW2, cb2, (float*)d_out, N);
}

// Round 3
// 780.565 us; speedup vs baseline: 2.2028x; 1.2067x over previous
//
#include <hip/hip_runtime.h>

#define HH 4  // heads

__device__ __forceinline__ float lrelu(float v){ return v > 0.f ? v : 0.2f*v; }

// h = X @ W  (W is [IC, 4*C] row-major), plus per-head attention logits
// block = 4*C threads, one node per block
template<int C>
__global__ void gemm_gat(const float* __restrict__ X, const float* __restrict__ W,
                         const float* __restrict__ a_s, const float* __restrict__ a_d,
                         float* __restrict__ h, float* __restrict__ als, float* __restrict__ ald,
                         int IC) {
    const int OC = 4*C;
    int n = blockIdx.x;
    int t = threadIdx.x;
    __shared__ float xs[128];
    for (int k = t; k < IC; k += OC) xs[k] = X[(size_t)n*IC + k];
    __syncthreads();
    float acc = 0.f;
    for (int k = 0; k < IC; ++k) acc += xs[k] * W[k*OC + t];
    h[(size_t)n*OC + t] = acc;
    int hh = t / C, c = t % C;
    float ps = acc * a_s[hh*C + c];
    float pd = acc * a_d[hh*C + c];
    #pragma unroll
    for (int m = 1; m < C; m <<= 1) { ps += __shfl_xor(ps, m); pd += __shfl_xor(pd, m); }
    if (c == 0) { als[n*HH + hh] = ps; ald[n*HH + hh] = pd; }
}

// ---------------- CSR build ----------------

__global__ void zero_i32(int* __restrict__ p, int n){
    int i = blockIdx.x*256 + threadIdx.x;
    if (i < n) p[i] = 0;
}

__global__ void count_deg(const int* __restrict__ ei, int* __restrict__ deg, int E){
    int e = blockIdx.x*256 + threadIdx.x;
    if (e < E) atomicAdd(&deg[ei[E + e]], 1);
}

__global__ void scan_deg(const int* __restrict__ deg, int* __restrict__ row_off,
                         int* __restrict__ cursor, int N){
    __shared__ int part[1024];
    int t = threadIdx.x;
    int chunk = (N + 1023) >> 10;
    int beg = t*chunk;
    int end = min(beg + chunk, N);
    int s = 0;
    for (int i = beg; i < end; ++i) s += deg[i];
    part[t] = s;
    __syncthreads();
    for (int off = 1; off < 1024; off <<= 1){
        int u = (t >= off) ? part[t - off] : 0;
        __syncthreads();
        part[t] += u;
        __syncthreads();
    }
    int o = part[t] - s;
    for (int i = beg; i < end; ++i){
        row_off[i] = o; cursor[i] = o; o += deg[i];
    }
    if (t == 1023) row_off[N] = part[1023];
}

__global__ void fill_csr(const int* __restrict__ ei, int* __restrict__ cursor,
                         int* __restrict__ ssrc, int E){
    int e = blockIdx.x*256 + threadIdx.x;
    if (e < E){
        int d = ei[E + e];
        int p = atomicAdd(&cursor[d], 1);
        ssrc[p] = ei[e];
    }
}

// ---------------- layer-3 prep: fold W3 into logit vectors + prescaled W3p ----------------
// ws3[hh][k] = sum_c W3[k, hh*64+c] * a3s[hh][c]   (same for wd3/a3d)
// W3p[(hh*64+k)*64 + c] = 0.25 * W3[k, hh*64+c]
__global__ void prep_l3(const float* __restrict__ W3, const float* __restrict__ a3s,
                        const float* __restrict__ a3d, float* __restrict__ ws3,
                        float* __restrict__ wd3, float* __restrict__ W3p){
    int t = threadIdx.x;          // 256 = (hh,k)
    int hh = t >> 6, k = t & 63;
    float ss = 0.f, sd = 0.f;
    for (int c = 0; c < 64; ++c){
        float w = W3[k*256 + hh*64 + c];
        ss += w * a3s[hh*64 + c];
        sd += w * a3d[hh*64 + c];
        W3p[t*64 + c] = 0.25f * w;
    }
    ws3[t] = ss; wd3[t] = sd;
}

// ---------------- fused segment-softmax + aggregate + bias + BN + ELU (concat layers) ----
// 4 nodes per 256-block, one wave per node. If L3PREP: also emit layer-3 logits from out row.
template<bool L3PREP>
__global__ void gat_agg16(const int* __restrict__ row_off, const int* __restrict__ ssrc,
                          const float* __restrict__ als, const float* __restrict__ ald,
                          const float* __restrict__ h, const float* __restrict__ b,
                          const float* __restrict__ g, const float* __restrict__ bb,
                          const float* __restrict__ bm, const float* __restrict__ bv,
                          float* __restrict__ out,
                          const float* __restrict__ ws3, const float* __restrict__ wd3,
                          float* __restrict__ als3, float* __restrict__ ald3, int N){
    int lane = threadIdx.x & 63;
    int n = blockIdx.x*4 + (threadIdx.x >> 6);
    if (n >= N) return;
    int hh = lane >> 4;
    float ad = ald[n*HH + hh];
    float vself = lrelu(als[n*HH + hh] + ad);
    int beg = row_off[n], end = row_off[n+1];
    float m = vself;
    for (int i = beg; i < end; ++i)
        m = fmaxf(m, lrelu(als[ssrc[i]*HH + hh] + ad));
    float den = __expf(vself - m);
    float acc = den * h[(size_t)n*64 + lane];
    for (int i = beg; i < end; ++i){
        int s = ssrc[i];
        float ex = __expf(lrelu(als[s*HH + hh] + ad) - m);
        den += ex;
        acc += ex * h[(size_t)s*64 + lane];
    }
    float val = acc/den + b[lane];
    val = g[lane]*(val - bm[lane])*rsqrtf(bv[lane] + 1e-5f) + bb[lane];
    val = val > 0.f ? val : expm1f(val);
    out[(size_t)n*64 + lane] = val;
    if (L3PREP){
        #pragma unroll
        for (int j = 0; j < 4; ++j){
            float ps = val * ws3[j*64 + lane];
            float pd = val * wd3[j*64 + lane];
            #pragma unroll
            for (int mm = 1; mm < 64; mm <<= 1){
                ps += __shfl_xor(ps, mm);
                pd += __shfl_xor(pd, mm);
            }
            if (lane == 0){ als3[n*HH + j] = ps; ald3[n*HH + j] = pd; }
        }
    }
}

// ---------------- layer-3 aggregation over hin (64 ch), 4 head-accs per lane ----------------
// y[(n*4+hh)*64 + k] = sum_s alpha_hh(s) * hin[s][k]
__global__ void gat_agg3(const int* __restrict__ row_off, const int* __restrict__ ssrc,
                         const float* __restrict__ als, const float* __restrict__ ald,
                         const float* __restrict__ hin, float* __restrict__ y, int N){
    int lane = threadIdx.x & 63;
    int n = blockIdx.x*4 + (threadIdx.x >> 6);
    if (n >= N) return;
    float4 ad = *(const float4*)(ald + n*4);
    float4 av = *(const float4*)(als + n*4);
    float v0 = lrelu(av.x + ad.x), v1 = lrelu(av.y + ad.y);
    float v2 = lrelu(av.z + ad.z), v3 = lrelu(av.w + ad.w);
    int beg = row_off[n], end = row_off[n+1];
    float m0 = v0, m1 = v1, m2 = v2, m3 = v3;
    for (int i = beg; i < end; ++i){
        float4 a = *(const float4*)(als + ssrc[i]*4);
        m0 = fmaxf(m0, lrelu(a.x + ad.x));
        m1 = fmaxf(m1, lrelu(a.y + ad.y));
        m2 = fmaxf(m2, lrelu(a.z + ad.z));
        m3 = fmaxf(m3, lrelu(a.w + ad.w));
    }
    float d0 = __expf(v0 - m0), d1 = __expf(v1 - m1);
    float d2 = __expf(v2 - m2), d3 = __expf(v3 - m3);
    float hv = hin[(size_t)n*64 + lane];
    float acc0 = d0*hv, acc1 = d1*hv, acc2 = d2*hv, acc3 = d3*hv;
    for (int i = beg; i < end; ++i){
        int s = ssrc[i];
        float4 a = *(const float4*)(als + s*4);
        float e0 = __expf(lrelu(a.x + ad.x) - m0);
        float e1 = __expf(lrelu(a.y + ad.y) - m1);
        float e2 = __expf(lrelu(a.z + ad.z) - m2);
        float e3 = __expf(lrelu(a.w + ad.w) - m3);
        float hs = hin[(size_t)s*64 + lane];
        d0 += e0; d1 += e1; d2 += e2; d3 += e3;
        acc0 += e0*hs; acc1 += e1*hs; acc2 += e2*hs; acc3 += e3*hs;
    }
    size_t base = (size_t)n*256 + lane;
    y[base]       = acc0/d0;
    y[base + 64]  = acc1/d1;
    y[base + 128] = acc2/d2;
    y[base + 192] = acc3/d3;
}

// ---------------- layer-3 post: out[n] = y[n,:256] @ W3p + b3, then BN ----------------
// 16 nodes per 256-block
__global__ void post_l3(const float* __restrict__ y, const float* __restrict__ W3p,
                        const float* __restrict__ b, const float* __restrict__ g,
                        const float* __restrict__ bb, const float* __restrict__ bm,
                        const float* __restrict__ bv, float* __restrict__ out, int N){
    __shared__ float ys[16*256];
    int t = threadIdx.x;
    int n0 = blockIdx.x*16;
    for (int i = t; i < 16*256; i += 256){
        int nl = i >> 8, j = i & 255;
        int n = n0 + nl;
        ys[i] = (n < N) ? y[(size_t)n*256 + j] : 0.f;
    }
    __syncthreads();
    int c = t & 63, nb = t >> 6;
    float acc[4] = {0.f, 0.f, 0.f, 0.f};
    for (int j = 0; j < 256; ++j){
        float w = W3p[j*64 + c];
        #pragma unroll
        for (int q = 0; q < 4; ++q)
            acc[q] += ys[(nb + 4*q)*256 + j] * w;
    }
    float scale = g[c]*rsqrtf(bv[c] + 1e-5f);
    #pragma unroll
    for (int q = 0; q < 4; ++q){
        int n = n0 + nb + 4*q;
        if (n < N){
            float val = acc[q] + b[c];
            out[(size_t)n*64 + c] = scale*(val - bm[c]) + bb[c];
        }
    }
}

__global__ void classifier(const float* __restrict__ hin, const float* __restrict__ cW1,
                           const float* __restrict__ cb1, const float* __restrict__ cW2,
                           const float* __restrict__ cb2, float* __restrict__ out, int N){
    __shared__ float w1[64*32];
    __shared__ float b1s[32], w2[32];
    int t = threadIdx.x;
    for (int k = t; k < 64*32; k += 256) w1[k] = cW1[k];
    if (t < 32) { b1s[t] = cb1[t]; w2[t] = cW2[t]; }
    __syncthreads();
    int n = blockIdx.x*256 + t;
    if (n >= N) return;
    float hrow[64];
    #pragma unroll
    for (int k = 0; k < 64; ++k) hrow[k] = hin[(size_t)n*64 + k];
    float acc2 = cb2[0];
    #pragma unroll 4
    for (int j = 0; j < 32; ++j) {
        float a = b1s[j];
        #pragma unroll
        for (int k = 0; k < 64; ++k) a += hrow[k]*w1[k*32 + j];
        float e = a > 0.f ? a : expm1f(a);
        acc2 += e * w2[j];
    }
    out[n] = acc2;
}

extern "C" void kernel_launch(void* const* d_in, const int* in_sizes, int n_in,
                              void* d_out, int out_size, void* d_ws, size_t ws_size,
                              hipStream_t stream) {
    const float* x    = (const float*)d_in[0];
    const int*   ei   = (const int*)  d_in[1];
    const float* W1   = (const float*)d_in[2];
    const float* a1s  = (const float*)d_in[3];
    const float* a1d  = (const float*)d_in[4];
    const float* b1   = (const float*)d_in[5];
    const float* W2   = (const float*)d_in[6];
    const float* a2s  = (const float*)d_in[7];
    const float* a2d  = (const float*)d_in[8];
    const float* b2   = (const float*)d_in[9];
    const float* W3   = (const float*)d_in[10];
    const float* a3s  = (const float*)d_in[11];
    const float* a3d  = (const float*)d_in[12];
    const float* b3   = (const float*)d_in[13];
    const float* bn1g = (const float*)d_in[14];
    const float* bn1b = (const float*)d_in[15];
    const float* bn1m = (const float*)d_in[16];
    const float* bn1v = (const float*)d_in[17];
    const float* bn2g = (const float*)d_in[18];
    const float* bn2b = (const float*)d_in[19];
    const float* bn2m = (const float*)d_in[20];
    const float* bn2v = (const float*)d_in[21];
    const float* bn3g = (const float*)d_in[22];
    const float* bn3b = (const float*)d_in[23];
    const float* bn3m = (const float*)d_in[24];
    const float* bn3v = (const float*)d_in[25];
    const float* cW1  = (const float*)d_in[26];
    const float* cb1  = (const float*)d_in[27];
    const float* cW2  = (const float*)d_in[28];
    const float* cb2  = (const float*)d_in[29];

    const int N = in_sizes[0] / 128;
    const int E = in_sizes[1] / 2;

    // ws layout (floats): h[64N] hin[64N] y[256N] als[4N] ald[4N] als3[4N] ald3[4N]
    //                     ws3[256] wd3[256] W3p[16384] | ints: deg[N] row_off[N+1] cursor[N] ssrc[E]
    float* h    = (float*)d_ws;
    float* hin  = h    + (size_t)N*64;
    float* y    = hin  + (size_t)N*64;
    float* als  = y    + (size_t)N*256;
    float* ald  = als  + (size_t)N*4;
    float* als3 = ald  + (size_t)N*4;
    float* ald3 = als3 + (size_t)N*4;
    float* ws3  = ald3 + (size_t)N*4;
    float* wd3  = ws3  + 256;
    float* W3p  = wd3  + 256;
    int* deg     = (int*)(W3p + 16384);
    int* row_off = deg + N;
    int* cursor  = row_off + (N + 1);
    int* ssrc    = cursor + N;

    const int B = 256;
    int gN  = (N + B-1)/B;
    int gE  = (E + B-1)/B;

    // ---- CSR build (dst-grouped src lists), reused by all 3 layers ----
    zero_i32<<<gN, B, 0, stream>>>(deg, N);
    count_deg<<<gE, B, 0, stream>>>(ei, deg, E);
    scan_deg<<<1, 1024, 0, stream>>>(deg, row_off, cursor, N);
    fill_csr<<<gE, B, 0, stream>>>(ei, cursor, ssrc, E);
    prep_l3<<<1, 256, 0, stream>>>(W3, a3s, a3d, ws3, wd3, W3p);

    // ---- layer 1 (IC=128, C=16, concat) ----
    gemm_gat<16><<<N, 64, 0, stream>>>(x, W1, a1s, a1d, h, als, ald, 128);
    gat_agg16<false><<<(N + 3)/4, B, 0, stream>>>(row_off, ssrc, als, ald, h, b1,
                                                  bn1g, bn1b, bn1m, bn1v, hin,
                                                  nullptr, nullptr, nullptr, nullptr, N);

    // ---- layer 2 (IC=64, C=16, concat) + layer-3 logits in epilogue ----
    gemm_gat<16><<<N, 64, 0, stream>>>(hin, W2, a2s, a2d, h, als, ald, 64);
    gat_agg16<true><<<(N + 3)/4, B, 0, stream>>>(row_off, ssrc, als, ald, h, b2,
                                                 bn2g, bn2b, bn2m, bn2v, hin,
                                                 ws3, wd3, als3, ald3, N);

    // ---- layer 3: aggregate hin directly, then per-head GEMM + mean + BN ----
    gat_agg3<<<(N + 3)/4, B, 0, stream>>>(row_off, ssrc, als3, ald3, hin, y, N);
    post_l3<<<(N + 15)/16, B, 0, stream>>>(y, W3p, b3, bn3g, bn3b, bn3m, bn3v, h, N);

    // ---- classifier ----
    classifier<<<gN, B, 0, stream>>>(h, cW1, cb1, cW2, cb2, (float*)d_out, N);
}

// Round 4
// 570.133 us; speedup vs baseline: 3.0158x; 1.3691x over previous
//
#include <hip/hip_runtime.h>

#define HH 4  // heads

__device__ __forceinline__ float lrelu(float v){ return v > 0.f ? v : 0.2f*v; }

// h = X @ W  (W is [IC, 4*C] row-major), plus per-head attention logits
// block = 4*C threads, one node per block
template<int C>
__global__ void gemm_gat(const float* __restrict__ X, const float* __restrict__ W,
                         const float* __restrict__ a_s, const float* __restrict__ a_d,
                         float* __restrict__ h, float* __restrict__ als, float* __restrict__ ald,
                         int IC) {
    const int OC = 4*C;
    int n = blockIdx.x;
    int t = threadIdx.x;
    __shared__ float xs[128];
    for (int k = t; k < IC; k += OC) xs[k] = X[(size_t)n*IC + k];
    __syncthreads();
    float acc = 0.f;
    for (int k = 0; k < IC; ++k) acc += xs[k] * W[k*OC + t];
    h[(size_t)n*OC + t] = acc;
    int hh = t / C, c = t % C;
    float ps = acc * a_s[hh*C + c];
    float pd = acc * a_d[hh*C + c];
    #pragma unroll
    for (int m = 1; m < C; m <<= 1) { ps += __shfl_xor(ps, m); pd += __shfl_xor(pd, m); }
    if (c == 0) { als[n*HH + hh] = ps; ald[n*HH + hh] = pd; }
}

// ---------------- CSR build ----------------

__global__ void zero_i32(int* __restrict__ p, int n){
    int i = blockIdx.x*256 + threadIdx.x;
    if (i < n) p[i] = 0;
}

__global__ void count_deg(const int* __restrict__ ei, int* __restrict__ deg, int E){
    int e = blockIdx.x*256 + threadIdx.x;
    if (e < E) atomicAdd(&deg[ei[E + e]], 1);
}

__global__ void scan_deg(const int* __restrict__ deg, int* __restrict__ row_off,
                         int* __restrict__ cursor, int N){
    __shared__ int part[1024];
    int t = threadIdx.x;
    int chunk = (N + 1023) >> 10;
    int beg = t*chunk;
    int end = min(beg + chunk, N);
    int s = 0;
    for (int i = beg; i < end; ++i) s += deg[i];
    part[t] = s;
    __syncthreads();
    for (int off = 1; off < 1024; off <<= 1){
        int u = (t >= off) ? part[t - off] : 0;
        __syncthreads();
        part[t] += u;
        __syncthreads();
    }
    int o = part[t] - s;
    for (int i = beg; i < end; ++i){
        row_off[i] = o; cursor[i] = o; o += deg[i];
    }
    if (t == 1023) row_off[N] = part[1023];
}

__global__ void fill_csr(const int* __restrict__ ei, int* __restrict__ cursor,
                         int* __restrict__ ssrc, int E){
    int e = blockIdx.x*256 + threadIdx.x;
    if (e < E){
        int d = ei[E + e];
        int p = atomicAdd(&cursor[d], 1);
        ssrc[p] = ei[e];
    }
}

// ---------------- layer-3 prep ----------------
__global__ void prep_l3(const float* __restrict__ W3, const float* __restrict__ a3s,
                        const float* __restrict__ a3d, float* __restrict__ ws3,
                        float* __restrict__ wd3, float* __restrict__ W3p){
    int t = threadIdx.x;          // 256 = (hh,k)
    int hh = t >> 6, k = t & 63;
    float ss = 0.f, sd = 0.f;
    for (int c = 0; c < 64; ++c){
        float w = W3[k*256 + hh*64 + c];
        ss += w * a3s[hh*64 + c];
        sd += w * a3d[hh*64 + c];
        W3p[t*64 + c] = 0.25f * w;
    }
    ws3[t] = ss; wd3[t] = sd;
}

// ---------------- fused segment-softmax + aggregate + bias + BN + ELU (concat layers) ----
// 4 nodes per 256-block, one wave per node. No max-shift (logits are O(1); exp safe in fp32).
// Chunked: lane (j = lane&15, hh = lane>>4) computes weight for edge cb+j, head hh, once;
// gather broadcasts weights/src via shfl. Denominator via 16-lane-group reduction.
template<bool L3PREP>
__global__ void gat_agg16(const int* __restrict__ row_off, const int* __restrict__ ssrc,
                          const float* __restrict__ als, const float* __restrict__ ald,
                          const float* __restrict__ h, const float* __restrict__ b,
                          const float* __restrict__ g, const float* __restrict__ bb,
                          const float* __restrict__ bm, const float* __restrict__ bv,
                          float* __restrict__ out,
                          const float* __restrict__ ws3, const float* __restrict__ wd3,
                          float* __restrict__ als3, float* __restrict__ ald3, int N){
    int lane = threadIdx.x & 63;
    int n = blockIdx.x*4 + (threadIdx.x >> 6);
    if (n >= N) return;
    int hh = lane >> 4, j = lane & 15;
    float ad = ald[n*HH + hh];
    float vself = __expf(lrelu(als[n*HH + hh] + ad));
    int beg = row_off[n], end = row_off[n+1];
    float denp = 0.f;
    float acc = vself * h[(size_t)n*64 + lane];
    for (int cb = beg; cb < end; cb += 16){
        int e = cb + j;
        int s = n; float ev = 0.f;
        if (e < end){ s = ssrc[e]; ev = __expf(lrelu(als[s*HH + hh] + ad)); }
        denp += ev;
        int cn = min(16, end - cb);
        int grp = lane & 48;
        for (int q = 0; q < cn; ++q){
            float w = __shfl(ev, grp | q);
            int  sq = __shfl(s,  grp | q);
            acc += w * h[(size_t)sq*64 + lane];
        }
    }
    #pragma unroll
    for (int m = 1; m < 16; m <<= 1) denp += __shfl_xor(denp, m);
    float den = vself + denp;
    float val = acc/den + b[lane];
    val = g[lane]*(val - bm[lane])*rsqrtf(bv[lane] + 1e-5f) + bb[lane];
    val = val > 0.f ? val : expm1f(val);
    out[(size_t)n*64 + lane] = val;
    if (L3PREP){
        #pragma unroll
        for (int jj = 0; jj < 4; ++jj){
            float ps = val * ws3[jj*64 + lane];
            float pd = val * wd3[jj*64 + lane];
            #pragma unroll
            for (int mm = 1; mm < 64; mm <<= 1){
                ps += __shfl_xor(ps, mm);
                pd += __shfl_xor(pd, mm);
            }
            if (lane == 0){ als3[n*HH + jj] = ps; ald3[n*HH + jj] = pd; }
        }
    }
}

// ---------------- layer-3 aggregation over hin (64 ch), 4 head-accs per lane --------------
// Chunks of 64 edges: lane computes the 4 head-weights for ONE edge; gather broadcasts.
__global__ void gat_agg3(const int* __restrict__ row_off, const int* __restrict__ ssrc,
                         const float* __restrict__ als, const float* __restrict__ ald,
                         const float* __restrict__ hin, float* __restrict__ y, int N){
    int lane = threadIdx.x & 63;
    int n = blockIdx.x*4 + (threadIdx.x >> 6);
    if (n >= N) return;
    float4 ad = *(const float4*)(ald + n*4);
    float4 av = *(const float4*)(als + n*4);
    float v0 = __expf(lrelu(av.x + ad.x)), v1 = __expf(lrelu(av.y + ad.y));
    float v2 = __expf(lrelu(av.z + ad.z)), v3 = __expf(lrelu(av.w + ad.w));
    int beg = row_off[n], end = row_off[n+1];
    float hv = hin[(size_t)n*64 + lane];
    float acc0 = v0*hv, acc1 = v1*hv, acc2 = v2*hv, acc3 = v3*hv;
    float dp0 = 0.f, dp1 = 0.f, dp2 = 0.f, dp3 = 0.f;
    for (int cb = beg; cb < end; cb += 64){
        int e = cb + lane;
        int s = n; float e0 = 0.f, e1 = 0.f, e2 = 0.f, e3 = 0.f;
        if (e < end){
            s = ssrc[e];
            float4 a = *(const float4*)(als + s*4);
            e0 = __expf(lrelu(a.x + ad.x));
            e1 = __expf(lrelu(a.y + ad.y));
            e2 = __expf(lrelu(a.z + ad.z));
            e3 = __expf(lrelu(a.w + ad.w));
        }
        dp0 += e0; dp1 += e1; dp2 += e2; dp3 += e3;
        int cn = min(64, end - cb);
        for (int q = 0; q < cn; ++q){
            float w0 = __shfl(e0, q), w1 = __shfl(e1, q);
            float w2 = __shfl(e2, q), w3 = __shfl(e3, q);
            int  sq = __shfl(s, q);
            float hs = hin[(size_t)sq*64 + lane];
            acc0 += w0*hs; acc1 += w1*hs; acc2 += w2*hs; acc3 += w3*hs;
        }
    }
    #pragma unroll
    for (int m = 1; m < 64; m <<= 1){
        dp0 += __shfl_xor(dp0, m); dp1 += __shfl_xor(dp1, m);
        dp2 += __shfl_xor(dp2, m); dp3 += __shfl_xor(dp3, m);
    }
    float d0 = v0 + dp0, d1 = v1 + dp1, d2 = v2 + dp2, d3 = v3 + dp3;
    size_t base = (size_t)n*256 + lane;
    y[base]       = acc0/d0;
    y[base + 64]  = acc1/d1;
    y[base + 128] = acc2/d2;
    y[base + 192] = acc3/d3;
}

// ---------------- layer-3 post: out[n] = y[n,:256] @ W3p + b3, then BN ----------------
__global__ void post_l3(const float* __restrict__ y, const float* __restrict__ W3p,
                        const float* __restrict__ b, const float* __restrict__ g,
                        const float* __restrict__ bb, const float* __restrict__ bm,
                        const float* __restrict__ bv, float* __restrict__ out, int N){
    __shared__ float ys[16*256];
    int t = threadIdx.x;
    int n0 = blockIdx.x*16;
    for (int i = t; i < 16*256; i += 256){
        int nl = i >> 8, j = i & 255;
        int n = n0 + nl;
        ys[i] = (n < N) ? y[(size_t)n*256 + j] : 0.f;
    }
    __syncthreads();
    int c = t & 63, nb = t >> 6;
    float acc[4] = {0.f, 0.f, 0.f, 0.f};
    for (int j = 0; j < 256; ++j){
        float w = W3p[j*64 + c];
        #pragma unroll
        for (int q = 0; q < 4; ++q)
            acc[q] += ys[(nb + 4*q)*256 + j] * w;
    }
    float scale = g[c]*rsqrtf(bv[c] + 1e-5f);
    #pragma unroll
    for (int q = 0; q < 4; ++q){
        int n = n0 + nb + 4*q;
        if (n < N){
            float val = acc[q] + b[c];
            out[(size_t)n*64 + c] = scale*(val - bm[c]) + bb[c];
        }
    }
}

__global__ void classifier(const float* __restrict__ hin, const float* __restrict__ cW1,
                           const float* __restrict__ cb1, const float* __restrict__ cW2,
                           const float* __restrict__ cb2, float* __restrict__ out, int N){
    __shared__ float w1[64*32];
    __shared__ float b1s[32], w2[32];
    int t = threadIdx.x;
    for (int k = t; k < 64*32; k += 256) w1[k] = cW1[k];
    if (t < 32) { b1s[t] = cb1[t]; w2[t] = cW2[t]; }
    __syncthreads();
    int n = blockIdx.x*256 + t;
    if (n >= N) return;
    float hrow[64];
    #pragma unroll
    for (int k = 0; k < 64; ++k) hrow[k] = hin[(size_t)n*64 + k];
    float acc2 = cb2[0];
    #pragma unroll 4
    for (int j = 0; j < 32; ++j) {
        float a = b1s[j];
        #pragma unroll
        for (int k = 0; k < 64; ++k) a += hrow[k]*w1[k*32 + j];
        float e = a > 0.f ? a : expm1f(a);
        acc2 += e * w2[j];
    }
    out[n] = acc2;
}

extern "C" void kernel_launch(void* const* d_in, const int* in_sizes, int n_in,
                              void* d_out, int out_size, void* d_ws, size_t ws_size,
                              hipStream_t stream) {
    const float* x    = (const float*)d_in[0];
    const int*   ei   = (const int*)  d_in[1];
    const float* W1   = (const float*)d_in[2];
    const float* a1s  = (const float*)d_in[3];
    const float* a1d  = (const float*)d_in[4];
    const float* b1   = (const float*)d_in[5];
    const float* W2   = (const float*)d_in[6];
    const float* a2s  = (const float*)d_in[7];
    const float* a2d  = (const float*)d_in[8];
    const float* b2   = (const float*)d_in[9];
    const float* W3   = (const float*)d_in[10];
    const float* a3s  = (const float*)d_in[11];
    const float* a3d  = (const float*)d_in[12];
    const float* b3   = (const float*)d_in[13];
    const float* bn1g = (const float*)d_in[14];
    const float* bn1b = (const float*)d_in[15];
    const float* bn1m = (const float*)d_in[16];
    const float* bn1v = (const float*)d_in[17];
    const float* bn2g = (const float*)d_in[18];
    const float* bn2b = (const float*)d_in[19];
    const float* bn2m = (const float*)d_in[20];
    const float* bn2v = (const float*)d_in[21];
    const float* bn3g = (const float*)d_in[22];
    const float* bn3b = (const float*)d_in[23];
    const float* bn3m = (const float*)d_in[24];
    const float* bn3v = (const float*)d_in[25];
    const float* cW1  = (const float*)d_in[26];
    const float* cb1  = (const float*)d_in[27];
    const float* cW2  = (const float*)d_in[28];
    const float* cb2  = (const float*)d_in[29];

    const int N = in_sizes[0] / 128;
    const int E = in_sizes[1] / 2;

    // ws layout (floats): h[64N] hin[64N] y[256N] als[4N] ald[4N] als3[4N] ald3[4N]
    //                     ws3[256] wd3[256] W3p[16384] | ints: deg[N] row_off[N+1] cursor[N] ssrc[E]
    float* h    = (float*)d_ws;
    float* hin  = h    + (size_t)N*64;
    float* y    = hin  + (size_t)N*64;
    float* als  = y    + (size_t)N*256;
    float* ald  = als  + (size_t)N*4;
    float* als3 = ald  + (size_t)N*4;
    float* ald3 = als3 + (size_t)N*4;
    float* ws3  = ald3 + (size_t)N*4;
    float* wd3  = ws3  + 256;
    float* W3p  = wd3  + 256;
    int* deg     = (int*)(W3p + 16384);
    int* row_off = deg + N;
    int* cursor  = row_off + (N + 1);
    int* ssrc    = cursor + N;

    const int B = 256;
    int gN  = (N + B-1)/B;
    int gE  = (E + B-1)/B;

    // ---- CSR build (dst-grouped src lists), reused by all 3 layers ----
    zero_i32<<<gN, B, 0, stream>>>(deg, N);
    count_deg<<<gE, B, 0, stream>>>(ei, deg, E);
    scan_deg<<<1, 1024, 0, stream>>>(deg, row_off, cursor, N);
    fill_csr<<<gE, B, 0, stream>>>(ei, cursor, ssrc, E);
    prep_l3<<<1, 256, 0, stream>>>(W3, a3s, a3d, ws3, wd3, W3p);

    // ---- layer 1 (IC=128, C=16, concat) ----
    gemm_gat<16><<<N, 64, 0, stream>>>(x, W1, a1s, a1d, h, als, ald, 128);
    gat_agg16<false><<<(N + 3)/4, B, 0, stream>>>(row_off, ssrc, als, ald, h, b1,
                                                  bn1g, bn1b, bn1m, bn1v, hin,
                                                  nullptr, nullptr, nullptr, nullptr, N);

    // ---- layer 2 (IC=64, C=16, concat) + layer-3 logits in epilogue ----
    gemm_gat<16><<<N, 64, 0, stream>>>(hin, W2, a2s, a2d, h, als, ald, 64);
    gat_agg16<true><<<(N + 3)/4, B, 0, stream>>>(row_off, ssrc, als, ald, h, b2,
                                                 bn2g, bn2b, bn2m, bn2v, hin,
                                                 ws3, wd3, als3, ald3, N);

    // ---- layer 3: aggregate hin directly, then per-head GEMM + mean + BN ----
    gat_agg3<<<(N + 3)/4, B, 0, stream>>>(row_off, ssrc, als3, ald3, hin, y, N);
    post_l3<<<(N + 15)/16, B, 0, stream>>>(y, W3p, b3, bn3g, bn3b, bn3m, bn3v, h, N);

    // ---- classifier ----
    classifier<<<gN, B, 0, stream>>>(h, cW1, cb1, cW2, cb2, (float*)d_out, N);
}

// Round 5
// 469.779 us; speedup vs baseline: 3.6601x; 1.2136x over previous
//
#include <hip/hip_runtime.h>

#define HH 4  // heads

__device__ __forceinline__ float lrelu(float v){ return v > 0.f ? v : 0.2f*v; }

// h = X @ W  (W is [IC, 4*C] row-major), plus per-head attention logits
// block = 4*C threads, one node per block
template<int C>
__global__ void gemm_gat(const float* __restrict__ X, const float* __restrict__ W,
                         const float* __restrict__ a_s, const float* __restrict__ a_d,
                         float* __restrict__ h, float* __restrict__ als, float* __restrict__ ald,
                         int IC) {
    const int OC = 4*C;
    int n = blockIdx.x;
    int t = threadIdx.x;
    __shared__ float xs[128];
    for (int k = t; k < IC; k += OC) xs[k] = X[(size_t)n*IC + k];
    __syncthreads();
    float acc = 0.f;
    for (int k = 0; k < IC; ++k) acc += xs[k] * W[k*OC + t];
    h[(size_t)n*OC + t] = acc;
    int hh = t / C, c = t % C;
    float ps = acc * a_s[hh*C + c];
    float pd = acc * a_d[hh*C + c];
    #pragma unroll
    for (int m = 1; m < C; m <<= 1) { ps += __shfl_xor(ps, m); pd += __shfl_xor(pd, m); }
    if (c == 0) { als[n*HH + hh] = ps; ald[n*HH + hh] = pd; }
}

// ---------------- CSR build ----------------

__global__ void zero_i32(int* __restrict__ p, int n){
    int i = blockIdx.x*256 + threadIdx.x;
    if (i < n) p[i] = 0;
}

__global__ void count_deg(const int* __restrict__ ei, int* __restrict__ deg, int E){
    int e = blockIdx.x*256 + threadIdx.x;
    if (e < E) atomicAdd(&deg[ei[E + e]], 1);
}

// multi-block scan, phase A: per-block (1024 vals) sums
__global__ void deg_bsum(const int* __restrict__ deg, int* __restrict__ bsum, int N){
    int t = threadIdx.x;
    int base = blockIdx.x*1024 + t*4;
    int s = 0;
    if (base + 3 < N){
        int4 v = *(const int4*)(deg + base);
        s = v.x + v.y + v.z + v.w;
    } else {
        for (int q = 0; q < 4; ++q) if (base + q < N) s += deg[base + q];
    }
    #pragma unroll
    for (int m = 1; m < 64; m <<= 1) s += __shfl_xor(s, m);
    __shared__ int ws[4];
    if ((t & 63) == 0) ws[t >> 6] = s;
    __syncthreads();
    if (t == 0) bsum[blockIdx.x] = ws[0] + ws[1] + ws[2] + ws[3];
}

// phase B: per-block exclusive scan + block offset (reduce preceding bsum in-kernel)
__global__ void scan_write(const int* __restrict__ deg, const int* __restrict__ bsum,
                           int* __restrict__ row_off, int* __restrict__ cursor, int N, int E){
    int t = threadIdx.x, bid = blockIdx.x, lane = t & 63, w = t >> 6;
    int base = bid*1024 + t*4;
    int v0 = 0, v1 = 0, v2 = 0, v3 = 0;
    if (base + 3 < N){
        int4 v = *(const int4*)(deg + base);
        v0 = v.x; v1 = v.y; v2 = v.z; v3 = v.w;
    } else {
        if (base     < N) v0 = deg[base];
        if (base + 1 < N) v1 = deg[base + 1];
        if (base + 2 < N) v2 = deg[base + 2];
        if (base + 3 < N) v3 = deg[base + 3];
    }
    int s = v0 + v1 + v2 + v3;
    // inclusive wave scan of thread sums
    int x = s;
    #pragma unroll
    for (int d = 1; d < 64; d <<= 1){
        int y = __shfl_up(x, d);
        if (lane >= d) x += y;
    }
    __shared__ int wsum[4];
    __shared__ int boff_s;
    if (lane == 63) wsum[w] = x;
    if (t < 64){
        int o = 0;
        for (int i = t; i < bid; i += 64) o += bsum[i];
        #pragma unroll
        for (int m = 1; m < 64; m <<= 1) o += __shfl_xor(o, m);
        if (t == 0) boff_s = o;
    }
    __syncthreads();
    int woff = 0;
    for (int i = 0; i < w; ++i) woff += wsum[i];
    int o = boff_s + woff + (x - s);  // exclusive prefix for this thread's first element
    if (base     < N){ row_off[base]     = o; cursor[base]     = o; o += v0; }
    if (base + 1 < N){ row_off[base + 1] = o; cursor[base + 1] = o; o += v1; }
    if (base + 2 < N){ row_off[base + 2] = o; cursor[base + 2] = o; o += v2; }
    if (base + 3 < N){ row_off[base + 3] = o; cursor[base + 3] = o; o += v3; }
    if (t == 0 && bid == 0) row_off[N] = E;
}

__global__ void fill_csr(const int* __restrict__ ei, int* __restrict__ cursor,
                         int* __restrict__ ssrc, int E){
    int e = blockIdx.x*256 + threadIdx.x;
    if (e < E){
        int d = ei[E + e];
        int p = atomicAdd(&cursor[d], 1);
        ssrc[p] = ei[e];
    }
}

// ---------------- layer-3 prep ----------------
__global__ void prep_l3(const float* __restrict__ W3, const float* __restrict__ a3s,
                        const float* __restrict__ a3d, float* __restrict__ ws3,
                        float* __restrict__ wd3, float* __restrict__ W3p){
    int t = threadIdx.x;          // 256 = (hh,k)
    int hh = t >> 6, k = t & 63;
    float ss = 0.f, sd = 0.f;
    for (int c = 0; c < 64; ++c){
        float w = W3[k*256 + hh*64 + c];
        ss += w * a3s[hh*64 + c];
        sd += w * a3d[hh*64 + c];
        W3p[t*64 + c] = 0.25f * w;
    }
    ws3[t] = ss; wd3[t] = sd;
}

// ---------------- fused segment-softmax + aggregate + bias + BN + ELU (concat layers) ----
template<bool L3PREP>
__global__ void gat_agg16(const int* __restrict__ row_off, const int* __restrict__ ssrc,
                          const float* __restrict__ als, const float* __restrict__ ald,
                          const float* __restrict__ h, const float* __restrict__ b,
                          const float* __restrict__ g, const float* __restrict__ bb,
                          const float* __restrict__ bm, const float* __restrict__ bv,
                          float* __restrict__ out,
                          const float* __restrict__ ws3, const float* __restrict__ wd3,
                          float* __restrict__ als3, float* __restrict__ ald3, int N){
    int lane = threadIdx.x & 63;
    int n = blockIdx.x*4 + (threadIdx.x >> 6);
    if (n >= N) return;
    int hh = lane >> 4, j = lane & 15;
    float ad = ald[n*HH + hh];
    float vself = __expf(lrelu(als[n*HH + hh] + ad));
    int beg = row_off[n], end = row_off[n+1];
    float denp = 0.f;
    float acc = vself * h[(size_t)n*64 + lane];
    for (int cb = beg; cb < end; cb += 16){
        int e = cb + j;
        int s = n; float ev = 0.f;
        if (e < end){ s = ssrc[e]; ev = __expf(lrelu(als[s*HH + hh] + ad)); }
        denp += ev;
        int cn = min(16, end - cb);
        int grp = lane & 48;
        for (int q = 0; q < cn; ++q){
            float w = __shfl(ev, grp | q);
            int  sq = __shfl(s,  grp | q);
            acc += w * h[(size_t)sq*64 + lane];
        }
    }
    #pragma unroll
    for (int m = 1; m < 16; m <<= 1) denp += __shfl_xor(denp, m);
    float den = vself + denp;
    float val = acc/den + b[lane];
    val = g[lane]*(val - bm[lane])*rsqrtf(bv[lane] + 1e-5f) + bb[lane];
    val = val > 0.f ? val : expm1f(val);
    out[(size_t)n*64 + lane] = val;
    if (L3PREP){
        #pragma unroll
        for (int jj = 0; jj < 4; ++jj){
            float ps = val * ws3[jj*64 + lane];
            float pd = val * wd3[jj*64 + lane];
            #pragma unroll
            for (int mm = 1; mm < 64; mm <<= 1){
                ps += __shfl_xor(ps, mm);
                pd += __shfl_xor(pd, mm);
            }
            if (lane == 0){ als3[n*HH + jj] = ps; ald3[n*HH + jj] = pd; }
        }
    }
}

// ---------------- layer-3 aggregation over hin (64 ch), 4 head-accs per lane --------------
__global__ void gat_agg3(const int* __restrict__ row_off, const int* __restrict__ ssrc,
                         const float* __restrict__ als, const float* __restrict__ ald,
                         const float* __restrict__ hin, float* __restrict__ y, int N){
    int lane = threadIdx.x & 63;
    int n = blockIdx.x*4 + (threadIdx.x >> 6);
    if (n >= N) return;
    float4 ad = *(const float4*)(ald + n*4);
    float4 av = *(const float4*)(als + n*4);
    float v0 = __expf(lrelu(av.x + ad.x)), v1 = __expf(lrelu(av.y + ad.y));
    float v2 = __expf(lrelu(av.z + ad.z)), v3 = __expf(lrelu(av.w + ad.w));
    int beg = row_off[n], end = row_off[n+1];
    float hv = hin[(size_t)n*64 + lane];
    float acc0 = v0*hv, acc1 = v1*hv, acc2 = v2*hv, acc3 = v3*hv;
    float dp0 = 0.f, dp1 = 0.f, dp2 = 0.f, dp3 = 0.f;
    for (int cb = beg; cb < end; cb += 64){
        int e = cb + lane;
        int s = n; float e0 = 0.f, e1 = 0.f, e2 = 0.f, e3 = 0.f;
        if (e < end){
            s = ssrc[e];
            float4 a = *(const float4*)(als + s*4);
            e0 = __expf(lrelu(a.x + ad.x));
            e1 = __expf(lrelu(a.y + ad.y));
            e2 = __expf(lrelu(a.z + ad.z));
            e3 = __expf(lrelu(a.w + ad.w));
        }
        dp0 += e0; dp1 += e1; dp2 += e2; dp3 += e3;
        int cn = min(64, end - cb);
        for (int q = 0; q < cn; ++q){
            float w0 = __shfl(e0, q), w1 = __shfl(e1, q);
            float w2 = __shfl(e2, q), w3 = __shfl(e3, q);
            int  sq = __shfl(s, q);
            float hs = hin[(size_t)sq*64 + lane];
            acc0 += w0*hs; acc1 += w1*hs; acc2 += w2*hs; acc3 += w3*hs;
        }
    }
    #pragma unroll
    for (int m = 1; m < 64; m <<= 1){
        dp0 += __shfl_xor(dp0, m); dp1 += __shfl_xor(dp1, m);
        dp2 += __shfl_xor(dp2, m); dp3 += __shfl_xor(dp3, m);
    }
    float d0 = v0 + dp0, d1 = v1 + dp1, d2 = v2 + dp2, d3 = v3 + dp3;
    size_t base = (size_t)n*256 + lane;
    y[base]       = acc0/d0;
    y[base + 64]  = acc1/d1;
    y[base + 128] = acc2/d2;
    y[base + 192] = acc3/d3;
}

// ---------------- layer-3 post: out[n] = y[n,:256] @ W3p + b3, then BN ----------------
__global__ void post_l3(const float* __restrict__ y, const float* __restrict__ W3p,
                        const float* __restrict__ b, const float* __restrict__ g,
                        const float* __restrict__ bb, const float* __restrict__ bm,
                        const float* __restrict__ bv, float* __restrict__ out, int N){
    __shared__ float ys[16*256];
    int t = threadIdx.x;
    int n0 = blockIdx.x*16;
    for (int i = t; i < 16*256; i += 256){
        int nl = i >> 8, j = i & 255;
        int n = n0 + nl;
        ys[i] = (n < N) ? y[(size_t)n*256 + j] : 0.f;
    }
    __syncthreads();
    int c = t & 63, nb = t >> 6;
    float acc[4] = {0.f, 0.f, 0.f, 0.f};
    for (int j = 0; j < 256; ++j){
        float w = W3p[j*64 + c];
        #pragma unroll
        for (int q = 0; q < 4; ++q)
            acc[q] += ys[(nb + 4*q)*256 + j] * w;
    }
    float scale = g[c]*rsqrtf(bv[c] + 1e-5f);
    #pragma unroll
    for (int q = 0; q < 4; ++q){
        int n = n0 + nb + 4*q;
        if (n < N){
            float val = acc[q] + b[c];
            out[(size_t)n*64 + c] = scale*(val - bm[c]) + bb[c];
        }
    }
}

__global__ void classifier(const float* __restrict__ hin, const float* __restrict__ cW1,
                           const float* __restrict__ cb1, const float* __restrict__ cW2,
                           const float* __restrict__ cb2, float* __restrict__ out, int N){
    __shared__ float w1[64*32];
    __shared__ float b1s[32], w2[32];
    int t = threadIdx.x;
    for (int k = t; k < 64*32; k += 256) w1[k] = cW1[k];
    if (t < 32) { b1s[t] = cb1[t]; w2[t] = cW2[t]; }
    __syncthreads();
    int n = blockIdx.x*256 + t;
    if (n >= N) return;
    float hrow[64];
    #pragma unroll
    for (int k = 0; k < 64; ++k) hrow[k] = hin[(size_t)n*64 + k];
    float acc2 = cb2[0];
    #pragma unroll 4
    for (int j = 0; j < 32; ++j) {
        float a = b1s[j];
        #pragma unroll
        for (int k = 0; k < 64; ++k) a += hrow[k]*w1[k*32 + j];
        float e = a > 0.f ? a : expm1f(a);
        acc2 += e * w2[j];
    }
    out[n] = acc2;
}

extern "C" void kernel_launch(void* const* d_in, const int* in_sizes, int n_in,
                              void* d_out, int out_size, void* d_ws, size_t ws_size,
                              hipStream_t stream) {
    const float* x    = (const float*)d_in[0];
    const int*   ei   = (const int*)  d_in[1];
    const float* W1   = (const float*)d_in[2];
    const float* a1s  = (const float*)d_in[3];
    const float* a1d  = (const float*)d_in[4];
    const float* b1   = (const float*)d_in[5];
    const float* W2   = (const float*)d_in[6];
    const float* a2s  = (const float*)d_in[7];
    const float* a2d  = (const float*)d_in[8];
    const float* b2   = (const float*)d_in[9];
    const float* W3   = (const float*)d_in[10];
    const float* a3s  = (const float*)d_in[11];
    const float* a3d  = (const float*)d_in[12];
    const float* b3   = (const float*)d_in[13];
    const float* bn1g = (const float*)d_in[14];
    const float* bn1b = (const float*)d_in[15];
    const float* bn1m = (const float*)d_in[16];
    const float* bn1v = (const float*)d_in[17];
    const float* bn2g = (const float*)d_in[18];
    const float* bn2b = (const float*)d_in[19];
    const float* bn2m = (const float*)d_in[20];
    const float* bn2v = (const float*)d_in[21];
    const float* bn3g = (const float*)d_in[22];
    const float* bn3b = (const float*)d_in[23];
    const float* bn3m = (const float*)d_in[24];
    const float* bn3v = (const float*)d_in[25];
    const float* cW1  = (const float*)d_in[26];
    const float* cb1  = (const float*)d_in[27];
    const float* cW2  = (const float*)d_in[28];
    const float* cb2  = (const float*)d_in[29];

    const int N = in_sizes[0] / 128;
    const int E = in_sizes[1] / 2;

    // ws layout (floats): h[64N] hin[64N] y[256N] als[4N] ald[4N] als3[4N] ald3[4N]
    //                     ws3[256] wd3[256] W3p[16384]
    // ints: deg[N] row_off[N+1] cursor[N] ssrc[E] bsum[NB]
    float* h    = (float*)d_ws;
    float* hin  = h    + (size_t)N*64;
    float* y    = hin  + (size_t)N*64;
    float* als  = y    + (size_t)N*256;
    float* ald  = als  + (size_t)N*4;
    float* als3 = ald  + (size_t)N*4;
    float* ald3 = als3 + (size_t)N*4;
    float* ws3  = ald3 + (size_t)N*4;
    float* wd3  = ws3  + 256;
    float* W3p  = wd3  + 256;
    int* deg     = (int*)(W3p + 16384);
    int* row_off = deg + N;
    int* cursor  = row_off + (N + 1);
    int* ssrc    = cursor + N;
    int* bsum    = ssrc + E;

    const int B = 256;
    int gN  = (N + B-1)/B;
    int gE  = (E + B-1)/B;
    int NB  = (N + 1023)/1024;

    // ---- CSR build (dst-grouped src lists), reused by all 3 layers ----
    zero_i32<<<gN, B, 0, stream>>>(deg, N);
    count_deg<<<gE, B, 0, stream>>>(ei, deg, E);
    deg_bsum<<<NB, B, 0, stream>>>(deg, bsum, N);
    scan_write<<<NB, B, 0, stream>>>(deg, bsum, row_off, cursor, N, E);
    fill_csr<<<gE, B, 0, stream>>>(ei, cursor, ssrc, E);
    prep_l3<<<1, 256, 0, stream>>>(W3, a3s, a3d, ws3, wd3, W3p);

    // ---- layer 1 (IC=128, C=16, concat) ----
    gemm_gat<16><<<N, 64, 0, stream>>>(x, W1, a1s, a1d, h, als, ald, 128);
    gat_agg16<false><<<(N + 3)/4, B, 0, stream>>>(row_off, ssrc, als, ald, h, b1,
                                                  bn1g, bn1b, bn1m, bn1v, hin,
                                                  nullptr, nullptr, nullptr, nullptr, N);

    // ---- layer 2 (IC=64, C=16, concat) + layer-3 logits in epilogue ----
    gemm_gat<16><<<N, 64, 0, stream>>>(hin, W2, a2s, a2d, h, als, ald, 64);
    gat_agg16<true><<<(N + 3)/4, B, 0, stream>>>(row_off, ssrc, als, ald, h, b2,
                                                 bn2g, bn2b, bn2m, bn2v, hin,
                                                 ws3, wd3, als3, ald3, N);

    // ---- layer 3: aggregate hin directly, then per-head GEMM + mean + BN ----
    gat_agg3<<<(N + 3)/4, B, 0, stream>>>(row_off, ssrc, als3, ald3, hin, y, N);
    post_l3<<<(N + 15)/16, B, 0, stream>>>(y, W3p, b3, bn3g, bn3b, bn3m, bn3v, h, N);

    // ---- classifier ----
    classifier<<<gN, B, 0, stream>>>(h, cW1, cb1, cW2, cb2, (float*)d_out, N);
}

// Round 6
// 420.718 us; speedup vs baseline: 4.0869x; 1.1166x over previous
//
#include <hip/hip_runtime.h>

#define HH 4  // heads

__device__ __forceinline__ float lrelu(float v){ return v > 0.f ? v : 0.2f*v; }

// h = X @ W  (W is [IC, 64] row-major), plus per-head attention logits (C=16).
// 256-thread block = 4 waves, one node per wave. Compile-time IC for unroll.
template<int IC>
__global__ void gemm_gat(const float* __restrict__ X, const float* __restrict__ W,
                         const float* __restrict__ a_s, const float* __restrict__ a_d,
                         float* __restrict__ h, float* __restrict__ als, float* __restrict__ ald,
                         int N) {
    int t = threadIdx.x, lane = t & 63, wid = t >> 6;
    int n = blockIdx.x*4 + wid;
    bool valid = n < N;
    int nc = valid ? n : N-1;
    __shared__ float xs[4][IC];
    #pragma unroll
    for (int k = lane; k < IC; k += 64) xs[wid][k] = X[(size_t)nc*IC + k];
    // same-wave LDS write->read; compiler inserts lgkmcnt, no cross-wave dep
    float acc = 0.f;
    #pragma unroll 8
    for (int k = 0; k < IC; ++k) acc += xs[wid][k] * W[k*64 + lane];
    if (valid) h[(size_t)nc*64 + lane] = acc;
    int hh = lane >> 4, c = lane & 15;
    float ps = acc * a_s[hh*16 + c];
    float pd = acc * a_d[hh*16 + c];
    #pragma unroll
    for (int m = 1; m < 16; m <<= 1){ ps += __shfl_xor(ps, m); pd += __shfl_xor(pd, m); }
    if (valid && c == 0){ als[nc*HH + hh] = ps; ald[nc*HH + hh] = pd; }
}

// ---------------- CSR build ----------------

__global__ void zero_i32(int* __restrict__ p, int n){
    int i = blockIdx.x*256 + threadIdx.x;
    if (i < n) p[i] = 0;
}

__global__ void count_deg(const int* __restrict__ ei, int* __restrict__ deg, int E){
    int e = blockIdx.x*256 + threadIdx.x;
    if (e < E) atomicAdd(&deg[ei[E + e]], 1);
}

// multi-block scan, phase A: per-block (1024 vals) sums
__global__ void deg_bsum(const int* __restrict__ deg, int* __restrict__ bsum, int N){
    int t = threadIdx.x;
    int base = blockIdx.x*1024 + t*4;
    int s = 0;
    if (base + 3 < N){
        int4 v = *(const int4*)(deg + base);
        s = v.x + v.y + v.z + v.w;
    } else {
        for (int q = 0; q < 4; ++q) if (base + q < N) s += deg[base + q];
    }
    #pragma unroll
    for (int m = 1; m < 64; m <<= 1) s += __shfl_xor(s, m);
    __shared__ int ws[4];
    if ((t & 63) == 0) ws[t >> 6] = s;
    __syncthreads();
    if (t == 0) bsum[blockIdx.x] = ws[0] + ws[1] + ws[2] + ws[3];
}

// phase B: per-block exclusive scan + block offset (reduce preceding bsum in-kernel)
__global__ void scan_write(const int* __restrict__ deg, const int* __restrict__ bsum,
                           int* __restrict__ row_off, int* __restrict__ cursor, int N, int E){
    int t = threadIdx.x, bid = blockIdx.x, lane = t & 63, w = t >> 6;
    int base = bid*1024 + t*4;
    int v0 = 0, v1 = 0, v2 = 0, v3 = 0;
    if (base + 3 < N){
        int4 v = *(const int4*)(deg + base);
        v0 = v.x; v1 = v.y; v2 = v.z; v3 = v.w;
    } else {
        if (base     < N) v0 = deg[base];
        if (base + 1 < N) v1 = deg[base + 1];
        if (base + 2 < N) v2 = deg[base + 2];
        if (base + 3 < N) v3 = deg[base + 3];
    }
    int s = v0 + v1 + v2 + v3;
    int x = s;
    #pragma unroll
    for (int d = 1; d < 64; d <<= 1){
        int y = __shfl_up(x, d);
        if (lane >= d) x += y;
    }
    __shared__ int wsum[4];
    __shared__ int boff_s;
    if (lane == 63) wsum[w] = x;
    if (t < 64){
        int o = 0;
        for (int i = t; i < bid; i += 64) o += bsum[i];
        #pragma unroll
        for (int m = 1; m < 64; m <<= 1) o += __shfl_xor(o, m);
        if (t == 0) boff_s = o;
    }
    __syncthreads();
    int woff = 0;
    for (int i = 0; i < w; ++i) woff += wsum[i];
    int o = boff_s + woff + (x - s);
    if (base     < N){ row_off[base]     = o; cursor[base]     = o; o += v0; }
    if (base + 1 < N){ row_off[base + 1] = o; cursor[base + 1] = o; o += v1; }
    if (base + 2 < N){ row_off[base + 2] = o; cursor[base + 2] = o; o += v2; }
    if (base + 3 < N){ row_off[base + 3] = o; cursor[base + 3] = o; o += v3; }
    if (t == 0 && bid == 0) row_off[N] = E;
}

__global__ void fill_csr(const int* __restrict__ ei, int* __restrict__ cursor,
                         int* __restrict__ ssrc, int E){
    int e = blockIdx.x*256 + threadIdx.x;
    if (e < E){
        int d = ei[E + e];
        int p = atomicAdd(&cursor[d], 1);
        ssrc[p] = ei[e];
    }
}

// ---------------- layer-3 prep ----------------
__global__ void prep_l3(const float* __restrict__ W3, const float* __restrict__ a3s,
                        const float* __restrict__ a3d, float* __restrict__ ws3,
                        float* __restrict__ wd3, float* __restrict__ W3p){
    int t = threadIdx.x;          // 256 = (hh,k)
    int hh = t >> 6, k = t & 63;
    float ss = 0.f, sd = 0.f;
    for (int c = 0; c < 64; ++c){
        float w = W3[k*256 + hh*64 + c];
        ss += w * a3s[hh*64 + c];
        sd += w * a3d[hh*64 + c];
        W3p[t*64 + c] = 0.25f * w;
    }
    ws3[t] = ss; wd3[t] = sd;
}

// ---------------- fused segment-softmax + aggregate + bias + BN + ELU (concat layers) ----
// 4 nodes per 256-block, one wave per node. Batched gathers (8 outstanding loads).
// Invalid tail edges: weight 0, src=self (L1-hot) -> no inner-loop branches.
template<bool L3PREP>
__global__ void gat_agg16(const int* __restrict__ row_off, const int* __restrict__ ssrc,
                          const float* __restrict__ als, const float* __restrict__ ald,
                          const float* __restrict__ h, const float* __restrict__ b,
                          const float* __restrict__ g, const float* __restrict__ bb,
                          const float* __restrict__ bm, const float* __restrict__ bv,
                          float* __restrict__ out,
                          const float* __restrict__ ws3, const float* __restrict__ wd3,
                          float* __restrict__ als3, float* __restrict__ ald3, int N){
    int lane = threadIdx.x & 63;
    int n = blockIdx.x*4 + (threadIdx.x >> 6);
    if (n >= N) return;   // no __syncthreads in this kernel
    int hh = lane >> 4, j = lane & 15, grp = lane & 48;
    float ad = ald[n*HH + hh];
    float vself = __expf(lrelu(als[n*HH + hh] + ad));
    int beg = row_off[n], end = row_off[n+1];
    float denp = 0.f;
    float acc = vself * h[(size_t)n*64 + lane];
    for (int cb = beg; cb < end; cb += 16){
        int e = cb + j;
        int s = n; float ev = 0.f;
        if (e < end){ s = ssrc[e]; ev = __expf(lrelu(als[s*HH + hh] + ad)); }
        denp += ev;
        #pragma unroll
        for (int qb = 0; qb < 16; qb += 8){
            int sq[8]; float hv[8];
            #pragma unroll
            for (int i = 0; i < 8; ++i) sq[i] = __shfl(s, grp | (qb + i));
            #pragma unroll
            for (int i = 0; i < 8; ++i) hv[i] = h[(size_t)sq[i]*64 + lane];
            #pragma unroll
            for (int i = 0; i < 8; ++i) acc += __shfl(ev, grp | (qb + i)) * hv[i];
        }
    }
    #pragma unroll
    for (int m = 1; m < 16; m <<= 1) denp += __shfl_xor(denp, m);
    float den = vself + denp;
    float val = acc/den + b[lane];
    val = g[lane]*(val - bm[lane])*rsqrtf(bv[lane] + 1e-5f) + bb[lane];
    val = val > 0.f ? val : expm1f(val);
    out[(size_t)n*64 + lane] = val;
    if (L3PREP){
        #pragma unroll
        for (int jj = 0; jj < 4; ++jj){
            float ps = val * ws3[jj*64 + lane];
            float pd = val * wd3[jj*64 + lane];
            #pragma unroll
            for (int mm = 1; mm < 64; mm <<= 1){
                ps += __shfl_xor(ps, mm);
                pd += __shfl_xor(pd, mm);
            }
            if (lane == 0){ als3[n*HH + jj] = ps; ald3[n*HH + jj] = pd; }
        }
    }
}

// ---------------- layer-3: aggregate hin (4 head-accs) + fused [256x64] GEMM + BN -------
// 4 nodes per 256-block, one wave per node; y kept in LDS (never hits global).
__global__ void gat_agg3_fused(const int* __restrict__ row_off, const int* __restrict__ ssrc,
                               const float* __restrict__ als, const float* __restrict__ ald,
                               const float* __restrict__ hin, const float* __restrict__ W3p,
                               const float* __restrict__ b, const float* __restrict__ g,
                               const float* __restrict__ bb, const float* __restrict__ bm,
                               const float* __restrict__ bv, float* __restrict__ out, int N){
    int t = threadIdx.x, lane = t & 63, wid = t >> 6;
    int n0 = blockIdx.x*4;
    int n = min(n0 + wid, N-1);          // clamp; no early return (syncthreads below)
    float4 adv = *(const float4*)(ald + n*4);
    float4 av  = *(const float4*)(als + n*4);
    float v0 = __expf(lrelu(av.x + adv.x)), v1 = __expf(lrelu(av.y + adv.y));
    float v2 = __expf(lrelu(av.z + adv.z)), v3 = __expf(lrelu(av.w + adv.w));
    int beg = row_off[n], end = row_off[n+1];
    float hv0 = hin[(size_t)n*64 + lane];
    float acc0 = v0*hv0, acc1 = v1*hv0, acc2 = v2*hv0, acc3 = v3*hv0;
    float dp0 = 0.f, dp1 = 0.f, dp2 = 0.f, dp3 = 0.f;
    for (int cb = beg; cb < end; cb += 64){
        int e = cb + lane;
        int s = n; float e0 = 0.f, e1 = 0.f, e2 = 0.f, e3 = 0.f;
        if (e < end){
            s = ssrc[e];
            float4 a = *(const float4*)(als + s*4);
            e0 = __expf(lrelu(a.x + adv.x));
            e1 = __expf(lrelu(a.y + adv.y));
            e2 = __expf(lrelu(a.z + adv.z));
            e3 = __expf(lrelu(a.w + adv.w));
        }
        dp0 += e0; dp1 += e1; dp2 += e2; dp3 += e3;
        int cn = min(64, end - cb);
        for (int qb = 0; qb < cn; qb += 8){
            int sq[8]; float hv[8];
            #pragma unroll
            for (int i = 0; i < 8; ++i) sq[i] = __shfl(s, qb + i);
            #pragma unroll
            for (int i = 0; i < 8; ++i) hv[i] = hin[(size_t)sq[i]*64 + lane];
            #pragma unroll
            for (int i = 0; i < 8; ++i){
                acc0 += __shfl(e0, qb + i)*hv[i];
                acc1 += __shfl(e1, qb + i)*hv[i];
                acc2 += __shfl(e2, qb + i)*hv[i];
                acc3 += __shfl(e3, qb + i)*hv[i];
            }
        }
    }
    #pragma unroll
    for (int m = 1; m < 64; m <<= 1){
        dp0 += __shfl_xor(dp0, m); dp1 += __shfl_xor(dp1, m);
        dp2 += __shfl_xor(dp2, m); dp3 += __shfl_xor(dp3, m);
    }
    __shared__ __align__(16) float ysh[4*256];
    ysh[wid*256 +   0 + lane] = acc0/(v0 + dp0);
    ysh[wid*256 +  64 + lane] = acc1/(v1 + dp1);
    ysh[wid*256 + 128 + lane] = acc2/(v2 + dp2);
    ysh[wid*256 + 192 + lane] = acc3/(v3 + dp3);
    __syncthreads();
    // per-wave mini-GEMM: out[n][c] = sum_j y[n][j] * W3p[j][c]
    float accp = 0.f;
    #pragma unroll 8
    for (int jb = 0; jb < 256; jb += 4){
        float4 yv = *(const float4*)&ysh[wid*256 + jb];
        accp += yv.x * W3p[(jb    )*64 + lane];
        accp += yv.y * W3p[(jb + 1)*64 + lane];
        accp += yv.z * W3p[(jb + 2)*64 + lane];
        accp += yv.w * W3p[(jb + 3)*64 + lane];
    }
    int nw = n0 + wid;
    if (nw < N){
        float val = accp + b[lane];
        out[(size_t)nw*64 + lane] = g[lane]*(val - bm[lane])*rsqrtf(bv[lane] + 1e-5f) + bb[lane];
    }
}

__global__ void classifier(const float* __restrict__ hin, const float* __restrict__ cW1,
                           const float* __restrict__ cb1, const float* __restrict__ cW2,
                           const float* __restrict__ cb2, float* __restrict__ out, int N){
    __shared__ float w1[64*32];
    __shared__ float b1s[32], w2[32];
    int t = threadIdx.x;
    for (int k = t; k < 64*32; k += 256) w1[k] = cW1[k];
    if (t < 32) { b1s[t] = cb1[t]; w2[t] = cW2[t]; }
    __syncthreads();
    int n = blockIdx.x*256 + t;
    if (n >= N) return;
    float hrow[64];
    #pragma unroll
    for (int k = 0; k < 64; ++k) hrow[k] = hin[(size_t)n*64 + k];
    float acc2 = cb2[0];
    #pragma unroll 4
    for (int j = 0; j < 32; ++j) {
        float a = b1s[j];
        #pragma unroll
        for (int k = 0; k < 64; ++k) a += hrow[k]*w1[k*32 + j];
        float e = a > 0.f ? a : expm1f(a);
        acc2 += e * w2[j];
    }
    out[n] = acc2;
}

extern "C" void kernel_launch(void* const* d_in, const int* in_sizes, int n_in,
                              void* d_out, int out_size, void* d_ws, size_t ws_size,
                              hipStream_t stream) {
    const float* x    = (const float*)d_in[0];
    const int*   ei   = (const int*)  d_in[1];
    const float* W1   = (const float*)d_in[2];
    const float* a1s  = (const float*)d_in[3];
    const float* a1d  = (const float*)d_in[4];
    const float* b1   = (const float*)d_in[5];
    const float* W2   = (const float*)d_in[6];
    const float* a2s  = (const float*)d_in[7];
    const float* a2d  = (const float*)d_in[8];
    const float* b2   = (const float*)d_in[9];
    const float* W3   = (const float*)d_in[10];
    const float* a3s  = (const float*)d_in[11];
    const float* a3d  = (const float*)d_in[12];
    const float* b3   = (const float*)d_in[13];
    const float* bn1g = (const float*)d_in[14];
    const float* bn1b = (const float*)d_in[15];
    const float* bn1m = (const float*)d_in[16];
    const float* bn1v = (const float*)d_in[17];
    const float* bn2g = (const float*)d_in[18];
    const float* bn2b = (const float*)d_in[19];
    const float* bn2m = (const float*)d_in[20];
    const float* bn2v = (const float*)d_in[21];
    const float* bn3g = (const float*)d_in[22];
    const float* bn3b = (const float*)d_in[23];
    const float* bn3m = (const float*)d_in[24];
    const float* bn3v = (const float*)d_in[25];
    const float* cW1  = (const float*)d_in[26];
    const float* cb1  = (const float*)d_in[27];
    const float* cW2  = (const float*)d_in[28];
    const float* cb2  = (const float*)d_in[29];

    const int N = in_sizes[0] / 128;
    const int E = in_sizes[1] / 2;

    // ws layout (floats): h[64N] hin[64N] als[4N] ald[4N] als3[4N] ald3[4N]
    //                     ws3[256] wd3[256] W3p[16384]
    // ints: deg[N] row_off[N+1] cursor[N] ssrc[E] bsum[NB]
    float* h    = (float*)d_ws;
    float* hin  = h    + (size_t)N*64;
    float* als  = hin  + (size_t)N*64;
    float* ald  = als  + (size_t)N*4;
    float* als3 = ald  + (size_t)N*4;
    float* ald3 = als3 + (size_t)N*4;
    float* ws3  = ald3 + (size_t)N*4;
    float* wd3  = ws3  + 256;
    float* W3p  = wd3  + 256;
    int* deg     = (int*)(W3p + 16384);
    int* row_off = deg + N;
    int* cursor  = row_off + (N + 1);
    int* ssrc    = cursor + N;
    int* bsum    = ssrc + E;

    const int B = 256;
    int gN  = (N + B-1)/B;
    int gE  = (E + B-1)/B;
    int NB  = (N + 1023)/1024;
    int gN4 = (N + 3)/4;

    // ---- CSR build (dst-grouped src lists), reused by all 3 layers ----
    zero_i32<<<gN, B, 0, stream>>>(deg, N);
    count_deg<<<gE, B, 0, stream>>>(ei, deg, E);
    deg_bsum<<<NB, B, 0, stream>>>(deg, bsum, N);
    scan_write<<<NB, B, 0, stream>>>(deg, bsum, row_off, cursor, N, E);
    fill_csr<<<gE, B, 0, stream>>>(ei, cursor, ssrc, E);
    prep_l3<<<1, 256, 0, stream>>>(W3, a3s, a3d, ws3, wd3, W3p);

    // ---- layer 1 (IC=128, C=16, concat) ----
    gemm_gat<128><<<gN4, B, 0, stream>>>(x, W1, a1s, a1d, h, als, ald, N);
    gat_agg16<false><<<gN4, B, 0, stream>>>(row_off, ssrc, als, ald, h, b1,
                                            bn1g, bn1b, bn1m, bn1v, hin,
                                            nullptr, nullptr, nullptr, nullptr, N);

    // ---- layer 2 (IC=64, C=16, concat) + layer-3 logits in epilogue ----
    gemm_gat<64><<<gN4, B, 0, stream>>>(hin, W2, a2s, a2d, h, als, ald, N);
    gat_agg16<true><<<gN4, B, 0, stream>>>(row_off, ssrc, als, ald, h, b2,
                                           bn2g, bn2b, bn2m, bn2v, hin,
                                           ws3, wd3, als3, ald3, N);

    // ---- layer 3: aggregate hin + fused per-head GEMM + mean + BN ----
    gat_agg3_fused<<<gN4, B, 0, stream>>>(row_off, ssrc, als3, ald3, hin, W3p,
                                          b3, bn3g, bn3b, bn3m, bn3v, h, N);

    // ---- classifier ----
    classifier<<<gN, B, 0, stream>>>(h, cW1, cb1, cW2, cb2, (float*)d_out, N);
}

// Round 7
// 401.575 us; speedup vs baseline: 4.2817x; 1.0477x over previous
//
#include <hip/hip_runtime.h>

#define HH 4  // heads

__device__ __forceinline__ float lrelu(float v){ return v > 0.f ? v : 0.2f*v; }

// h = X @ W  (W is [IC, 64] row-major), plus per-head attention logits (C=16).
// 256-thread block = 4 waves, one node per wave. Compile-time IC for unroll.
template<int IC>
__global__ void gemm_gat(const float* __restrict__ X, const float* __restrict__ W,
                         const float* __restrict__ a_s, const float* __restrict__ a_d,
                         float* __restrict__ h, float* __restrict__ als, float* __restrict__ ald,
                         int N) {
    int t = threadIdx.x, lane = t & 63, wid = t >> 6;
    int n = blockIdx.x*4 + wid;
    bool valid = n < N;
    int nc = valid ? n : N-1;
    __shared__ float xs[4][IC];
    #pragma unroll
    for (int k = lane; k < IC; k += 64) xs[wid][k] = X[(size_t)nc*IC + k];
    float acc = 0.f;
    #pragma unroll 8
    for (int k = 0; k < IC; ++k) acc += xs[wid][k] * W[k*64 + lane];
    if (valid) h[(size_t)nc*64 + lane] = acc;
    int hh = lane >> 4, c = lane & 15;
    float ps = acc * a_s[hh*16 + c];
    float pd = acc * a_d[hh*16 + c];
    #pragma unroll
    for (int m = 1; m < 16; m <<= 1){ ps += __shfl_xor(ps, m); pd += __shfl_xor(pd, m); }
    if (valid && c == 0){ als[nc*HH + hh] = ps; ald[nc*HH + hh] = pd; }
}

// ---------------- CSR build ----------------

__global__ void zero_i32(int* __restrict__ p, int n){
    int i = blockIdx.x*256 + threadIdx.x;
    if (i < n) p[i] = 0;
}

__global__ void count_deg(const int* __restrict__ ei, int* __restrict__ deg, int E){
    int e = blockIdx.x*256 + threadIdx.x;
    if (e < E) atomicAdd(&deg[ei[E + e]], 1);
}

// multi-block scan, phase A: per-block (1024 vals) sums
__global__ void deg_bsum(const int* __restrict__ deg, int* __restrict__ bsum, int N){
    int t = threadIdx.x;
    int base = blockIdx.x*1024 + t*4;
    int s = 0;
    if (base + 3 < N){
        int4 v = *(const int4*)(deg + base);
        s = v.x + v.y + v.z + v.w;
    } else {
        for (int q = 0; q < 4; ++q) if (base + q < N) s += deg[base + q];
    }
    #pragma unroll
    for (int m = 1; m < 64; m <<= 1) s += __shfl_xor(s, m);
    __shared__ int ws[4];
    if ((t & 63) == 0) ws[t >> 6] = s;
    __syncthreads();
    if (t == 0) bsum[blockIdx.x] = ws[0] + ws[1] + ws[2] + ws[3];
}

// phase B: per-block exclusive scan + block offset (reduce preceding bsum in-kernel)
__global__ void scan_write(const int* __restrict__ deg, const int* __restrict__ bsum,
                           int* __restrict__ row_off, int* __restrict__ cursor, int N, int E){
    int t = threadIdx.x, bid = blockIdx.x, lane = t & 63, w = t >> 6;
    int base = bid*1024 + t*4;
    int v0 = 0, v1 = 0, v2 = 0, v3 = 0;
    if (base + 3 < N){
        int4 v = *(const int4*)(deg + base);
        v0 = v.x; v1 = v.y; v2 = v.z; v3 = v.w;
    } else {
        if (base     < N) v0 = deg[base];
        if (base + 1 < N) v1 = deg[base + 1];
        if (base + 2 < N) v2 = deg[base + 2];
        if (base + 3 < N) v3 = deg[base + 3];
    }
    int s = v0 + v1 + v2 + v3;
    int x = s;
    #pragma unroll
    for (int d = 1; d < 64; d <<= 1){
        int y = __shfl_up(x, d);
        if (lane >= d) x += y;
    }
    __shared__ int wsum[4];
    __shared__ int boff_s;
    if (lane == 63) wsum[w] = x;
    if (t < 64){
        int o = 0;
        for (int i = t; i < bid; i += 64) o += bsum[i];
        #pragma unroll
        for (int m = 1; m < 64; m <<= 1) o += __shfl_xor(o, m);
        if (t == 0) boff_s = o;
    }
    __syncthreads();
    int woff = 0;
    for (int i = 0; i < w; ++i) woff += wsum[i];
    int o = boff_s + woff + (x - s);
    if (base     < N){ row_off[base]     = o; cursor[base]     = o; o += v0; }
    if (base + 1 < N){ row_off[base + 1] = o; cursor[base + 1] = o; o += v1; }
    if (base + 2 < N){ row_off[base + 2] = o; cursor[base + 2] = o; o += v2; }
    if (base + 3 < N){ row_off[base + 3] = o; cursor[base + 3] = o; o += v3; }
    if (t == 0 && bid == 0) row_off[N] = E;
}

__global__ void fill_csr(const int* __restrict__ ei, int* __restrict__ cursor,
                         int* __restrict__ ssrc, int E){
    int e = blockIdx.x*256 + threadIdx.x;
    if (e < E){
        int d = ei[E + e];
        int p = atomicAdd(&cursor[d], 1);
        ssrc[p] = ei[e];
    }
}

// ---------------- layer-3 prep ----------------
__global__ void prep_l3(const float* __restrict__ W3, const float* __restrict__ a3s,
                        const float* __restrict__ a3d, float* __restrict__ ws3,
                        float* __restrict__ wd3, float* __restrict__ W3p){
    int t = threadIdx.x;          // 256 = (hh,k)
    int hh = t >> 6, k = t & 63;
    float ss = 0.f, sd = 0.f;
    for (int c = 0; c < 64; ++c){
        float w = W3[k*256 + hh*64 + c];
        ss += w * a3s[hh*64 + c];
        sd += w * a3d[hh*64 + c];
        W3p[t*64 + c] = 0.25f * w;
    }
    ws3[t] = ss; wd3[t] = sd;
}

// ---------------- fused segment-softmax + aggregate + bias + BN + ELU (concat layers) ----
// 4 nodes per 256-block, one wave per node. Batched gathers (8 outstanding loads).
template<bool L3PREP>
__global__ void gat_agg16(const int* __restrict__ row_off, const int* __restrict__ ssrc,
                          const float* __restrict__ als, const float* __restrict__ ald,
                          const float* __restrict__ h, const float* __restrict__ b,
                          const float* __restrict__ g, const float* __restrict__ bb,
                          const float* __restrict__ bm, const float* __restrict__ bv,
                          float* __restrict__ out,
                          const float* __restrict__ ws3, const float* __restrict__ wd3,
                          float* __restrict__ als3, float* __restrict__ ald3, int N){
    int lane = threadIdx.x & 63;
    int n = blockIdx.x*4 + (threadIdx.x >> 6);
    if (n >= N) return;   // no __syncthreads in this kernel
    int hh = lane >> 4, j = lane & 15, grp = lane & 48;
    float ad = ald[n*HH + hh];
    float vself = __expf(lrelu(als[n*HH + hh] + ad));
    int beg = row_off[n], end = row_off[n+1];
    float denp = 0.f;
    float acc = vself * h[(size_t)n*64 + lane];
    for (int cb = beg; cb < end; cb += 16){
        int e = cb + j;
        int s = n; float ev = 0.f;
        if (e < end){ s = ssrc[e]; ev = __expf(lrelu(als[s*HH + hh] + ad)); }
        denp += ev;
        #pragma unroll
        for (int qb = 0; qb < 16; qb += 8){
            int sq[8]; float hv[8];
            #pragma unroll
            for (int i = 0; i < 8; ++i) sq[i] = __shfl(s, grp | (qb + i));
            #pragma unroll
            for (int i = 0; i < 8; ++i) hv[i] = h[(size_t)sq[i]*64 + lane];
            #pragma unroll
            for (int i = 0; i < 8; ++i) acc += __shfl(ev, grp | (qb + i)) * hv[i];
        }
    }
    #pragma unroll
    for (int m = 1; m < 16; m <<= 1) denp += __shfl_xor(denp, m);
    float den = vself + denp;
    float val = acc/den + b[lane];
    val = g[lane]*(val - bm[lane])*rsqrtf(bv[lane] + 1e-5f) + bb[lane];
    val = val > 0.f ? val : expm1f(val);
    out[(size_t)n*64 + lane] = val;
    if (L3PREP){
        #pragma unroll
        for (int jj = 0; jj < 4; ++jj){
            float ps = val * ws3[jj*64 + lane];
            float pd = val * wd3[jj*64 + lane];
            #pragma unroll
            for (int mm = 1; mm < 64; mm <<= 1){
                ps += __shfl_xor(ps, mm);
                pd += __shfl_xor(pd, mm);
            }
            if (lane == 0){ als3[n*HH + jj] = ps; ald3[n*HH + jj] = pd; }
        }
    }
}

// ---------------- layer-3: aggregate hin (4 head-accs) + cooperative GEMM + BN -----------
// 4 nodes per 256-block, one wave per node for aggregation.
// GEMM phase: wave w handles j-slice [w*64,(w+1)*64) for ALL 4 nodes (4x less W3p traffic),
// then cross-wave LDS reduction. Weights/src distributed via per-wave LDS (broadcast reads).
__global__ void gat_agg3_fused(const int* __restrict__ row_off, const int* __restrict__ ssrc,
                               const float* __restrict__ als, const float* __restrict__ ald,
                               const float* __restrict__ hin, const float* __restrict__ W3p,
                               const float* __restrict__ b, const float* __restrict__ g,
                               const float* __restrict__ bb, const float* __restrict__ bm,
                               const float* __restrict__ bv, float* __restrict__ out, int N){
    int t = threadIdx.x, lane = t & 63, wid = t >> 6;
    int n0 = blockIdx.x*4;
    int n = min(n0 + wid, N-1);          // clamp; no early return (syncthreads below)
    __shared__ __align__(16) float4 wlds[4][64];
    __shared__ int slds[4][64];
    __shared__ __align__(16) float ysh[4*256];
    __shared__ float red[4][4][64];      // [wave][node][lane]
    float4 adv = *(const float4*)(ald + n*4);
    float4 av  = *(const float4*)(als + n*4);
    float v0 = __expf(lrelu(av.x + adv.x)), v1 = __expf(lrelu(av.y + adv.y));
    float v2 = __expf(lrelu(av.z + adv.z)), v3 = __expf(lrelu(av.w + adv.w));
    int beg = row_off[n], end = row_off[n+1];
    float hv0 = hin[(size_t)n*64 + lane];
    float acc0 = v0*hv0, acc1 = v1*hv0, acc2 = v2*hv0, acc3 = v3*hv0;
    float dp0 = 0.f, dp1 = 0.f, dp2 = 0.f, dp3 = 0.f;
    for (int cb = beg; cb < end; cb += 64){
        int e = cb + lane;
        int s = n; float e0 = 0.f, e1 = 0.f, e2 = 0.f, e3 = 0.f;
        if (e < end){
            s = ssrc[e];
            float4 a = *(const float4*)(als + s*4);
            e0 = __expf(lrelu(a.x + adv.x));
            e1 = __expf(lrelu(a.y + adv.y));
            e2 = __expf(lrelu(a.z + adv.z));
            e3 = __expf(lrelu(a.w + adv.w));
        }
        dp0 += e0; dp1 += e1; dp2 += e2; dp3 += e3;
        wlds[wid][lane] = make_float4(e0, e1, e2, e3);   // same-wave produce/consume
        slds[wid][lane] = s;
        int cn = min(64, end - cb);
        for (int qb = 0; qb < cn; qb += 8){
            int sq[8]; float hv[8]; float4 wv[8];
            #pragma unroll
            for (int i = 0; i < 8; ++i) sq[i] = slds[wid][qb + i];
            #pragma unroll
            for (int i = 0; i < 8; ++i) hv[i] = hin[(size_t)sq[i]*64 + lane];
            #pragma unroll
            for (int i = 0; i < 8; ++i) wv[i] = wlds[wid][qb + i];
            #pragma unroll
            for (int i = 0; i < 8; ++i){
                acc0 += wv[i].x*hv[i];
                acc1 += wv[i].y*hv[i];
                acc2 += wv[i].z*hv[i];
                acc3 += wv[i].w*hv[i];
            }
        }
    }
    #pragma unroll
    for (int m = 1; m < 64; m <<= 1){
        dp0 += __shfl_xor(dp0, m); dp1 += __shfl_xor(dp1, m);
        dp2 += __shfl_xor(dp2, m); dp3 += __shfl_xor(dp3, m);
    }
    ysh[wid*256 +   0 + lane] = acc0/(v0 + dp0);
    ysh[wid*256 +  64 + lane] = acc1/(v1 + dp1);
    ysh[wid*256 + 128 + lane] = acc2/(v2 + dp2);
    ysh[wid*256 + 192 + lane] = acc3/(v3 + dp3);
    __syncthreads();
    // cooperative GEMM: wave wid covers j in [wid*64, wid*64+64) for all 4 nodes
    float a0 = 0.f, a1 = 0.f, a2 = 0.f, a3 = 0.f;
    int jbase = wid*64;
    #pragma unroll 4
    for (int jj = 0; jj < 64; jj += 4){
        int jb = jbase + jj;
        float4 y0 = *(const float4*)&ysh[0*256 + jb];
        float4 y1 = *(const float4*)&ysh[1*256 + jb];
        float4 y2 = *(const float4*)&ysh[2*256 + jb];
        float4 y3 = *(const float4*)&ysh[3*256 + jb];
        float w0 = W3p[(jb    )*64 + lane];
        float w1 = W3p[(jb + 1)*64 + lane];
        float w2 = W3p[(jb + 2)*64 + lane];
        float w3 = W3p[(jb + 3)*64 + lane];
        a0 += y0.x*w0 + y0.y*w1 + y0.z*w2 + y0.w*w3;
        a1 += y1.x*w0 + y1.y*w1 + y1.z*w2 + y1.w*w3;
        a2 += y2.x*w0 + y2.y*w1 + y2.z*w2 + y2.w*w3;
        a3 += y3.x*w0 + y3.y*w1 + y3.z*w2 + y3.w*w3;
    }
    red[wid][0][lane] = a0;
    red[wid][1][lane] = a1;
    red[wid][2][lane] = a2;
    red[wid][3][lane] = a3;
    __syncthreads();
    // wave wid finalizes node n0+wid
    int nw = n0 + wid;
    if (nw < N){
        float val = red[0][wid][lane] + red[1][wid][lane] +
                    red[2][wid][lane] + red[3][wid][lane] + b[lane];
        out[(size_t)nw*64 + lane] = g[lane]*(val - bm[lane])*rsqrtf(bv[lane] + 1e-5f) + bb[lane];
    }
}

__global__ void classifier(const float* __restrict__ hin, const float* __restrict__ cW1,
                           const float* __restrict__ cb1, const float* __restrict__ cW2,
                           const float* __restrict__ cb2, float* __restrict__ out, int N){
    __shared__ float w1[64*32];
    __shared__ float b1s[32], w2[32];
    int t = threadIdx.x;
    for (int k = t; k < 64*32; k += 256) w1[k] = cW1[k];
    if (t < 32) { b1s[t] = cb1[t]; w2[t] = cW2[t]; }
    __syncthreads();
    int n = blockIdx.x*256 + t;
    if (n >= N) return;
    float hrow[64];
    #pragma unroll
    for (int k = 0; k < 64; ++k) hrow[k] = hin[(size_t)n*64 + k];
    float acc2 = cb2[0];
    #pragma unroll 4
    for (int j = 0; j < 32; ++j) {
        float a = b1s[j];
        #pragma unroll
        for (int k = 0; k < 64; ++k) a += hrow[k]*w1[k*32 + j];
        float e = a > 0.f ? a : expm1f(a);
        acc2 += e * w2[j];
    }
    out[n] = acc2;
}

extern "C" void kernel_launch(void* const* d_in, const int* in_sizes, int n_in,
                              void* d_out, int out_size, void* d_ws, size_t ws_size,
                              hipStream_t stream) {
    const float* x    = (const float*)d_in[0];
    const int*   ei   = (const int*)  d_in[1];
    const float* W1   = (const float*)d_in[2];
    const float* a1s  = (const float*)d_in[3];
    const float* a1d  = (const float*)d_in[4];
    const float* b1   = (const float*)d_in[5];
    const float* W2   = (const float*)d_in[6];
    const float* a2s  = (const float*)d_in[7];
    const float* a2d  = (const float*)d_in[8];
    const float* b2   = (const float*)d_in[9];
    const float* W3   = (const float*)d_in[10];
    const float* a3s  = (const float*)d_in[11];
    const float* a3d  = (const float*)d_in[12];
    const float* b3   = (const float*)d_in[13];
    const float* bn1g = (const float*)d_in[14];
    const float* bn1b = (const float*)d_in[15];
    const float* bn1m = (const float*)d_in[16];
    const float* bn1v = (const float*)d_in[17];
    const float* bn2g = (const float*)d_in[18];
    const float* bn2b = (const float*)d_in[19];
    const float* bn2m = (const float*)d_in[20];
    const float* bn2v = (const float*)d_in[21];
    const float* bn3g = (const float*)d_in[22];
    const float* bn3b = (const float*)d_in[23];
    const float* bn3m = (const float*)d_in[24];
    const float* bn3v = (const float*)d_in[25];
    const float* cW1  = (const float*)d_in[26];
    const float* cb1  = (const float*)d_in[27];
    const float* cW2  = (const float*)d_in[28];
    const float* cb2  = (const float*)d_in[29];

    const int N = in_sizes[0] / 128;
    const int E = in_sizes[1] / 2;

    // ws layout (floats): h[64N] hin[64N] als[4N] ald[4N] als3[4N] ald3[4N]
    //                     ws3[256] wd3[256] W3p[16384]
    // ints: deg[N] row_off[N+1] cursor[N] ssrc[E] bsum[NB]
    float* h    = (float*)d_ws;
    float* hin  = h    + (size_t)N*64;
    float* als  = hin  + (size_t)N*64;
    float* ald  = als  + (size_t)N*4;
    float* als3 = ald  + (size_t)N*4;
    float* ald3 = als3 + (size_t)N*4;
    float* ws3  = ald3 + (size_t)N*4;
    float* wd3  = ws3  + 256;
    float* W3p  = wd3  + 256;
    int* deg     = (int*)(W3p + 16384);
    int* row_off = deg + N;
    int* cursor  = row_off + (N + 1);
    int* ssrc    = cursor + N;
    int* bsum    = ssrc + E;

    const int B = 256;
    int gN  = (N + B-1)/B;
    int gE  = (E + B-1)/B;
    int NB  = (N + 1023)/1024;
    int gN4 = (N + 3)/4;

    // ---- CSR build (dst-grouped src lists), reused by all 3 layers ----
    zero_i32<<<gN, B, 0, stream>>>(deg, N);
    count_deg<<<gE, B, 0, stream>>>(ei, deg, E);
    deg_bsum<<<NB, B, 0, stream>>>(deg, bsum, N);
    scan_write<<<NB, B, 0, stream>>>(deg, bsum, row_off, cursor, N, E);
    fill_csr<<<gE, B, 0, stream>>>(ei, cursor, ssrc, E);
    prep_l3<<<1, 256, 0, stream>>>(W3, a3s, a3d, ws3, wd3, W3p);

    // ---- layer 1 (IC=128, C=16, concat) ----
    gemm_gat<128><<<gN4, B, 0, stream>>>(x, W1, a1s, a1d, h, als, ald, N);
    gat_agg16<false><<<gN4, B, 0, stream>>>(row_off, ssrc, als, ald, h, b1,
                                            bn1g, bn1b, bn1m, bn1v, hin,
                                            nullptr, nullptr, nullptr, nullptr, N);

    // ---- layer 2 (IC=64, C=16, concat) + layer-3 logits in epilogue ----
    gemm_gat<64><<<gN4, B, 0, stream>>>(hin, W2, a2s, a2d, h, als, ald, N);
    gat_agg16<true><<<gN4, B, 0, stream>>>(row_off, ssrc, als, ald, h, b2,
                                           bn2g, bn2b, bn2m, bn2v, hin,
                                           ws3, wd3, als3, ald3, N);

    // ---- layer 3: aggregate hin + cooperative per-block GEMM + mean + BN ----
    gat_agg3_fused<<<gN4, B, 0, stream>>>(row_off, ssrc, als3, ald3, hin, W3p,
                                          b3, bn3g, bn3b, bn3m, bn3v, h, N);

    // ---- classifier ----
    classifier<<<gN, B, 0, stream>>>(h, cW1, cb1, cW2, cb2, (float*)d_out, N);
}

// Round 8
// 386.451 us; speedup vs baseline: 4.4492x; 1.0391x over previous
//
#include <hip/hip_runtime.h>

#define HH 4  // heads

__device__ __forceinline__ float lrelu(float v){ return v > 0.f ? v : 0.2f*v; }

// h = X @ W  (W is [IC, 64] row-major), plus per-head attention logits (C=16).
// 256-thread block = 4 waves, one node per wave. Compile-time IC for unroll.
template<int IC>
__global__ void gemm_gat(const float* __restrict__ X, const float* __restrict__ W,
                         const float* __restrict__ a_s, const float* __restrict__ a_d,
                         float* __restrict__ h, float* __restrict__ als, float* __restrict__ ald,
                         int N) {
    int t = threadIdx.x, lane = t & 63, wid = t >> 6;
    int n = blockIdx.x*4 + wid;
    bool valid = n < N;
    int nc = valid ? n : N-1;
    __shared__ float xs[4][IC];
    #pragma unroll
    for (int k = lane; k < IC; k += 64) xs[wid][k] = X[(size_t)nc*IC + k];
    float acc = 0.f;
    #pragma unroll 8
    for (int k = 0; k < IC; ++k) acc += xs[wid][k] * W[k*64 + lane];
    if (valid) h[(size_t)nc*64 + lane] = acc;
    int hh = lane >> 4, c = lane & 15;
    float ps = acc * a_s[hh*16 + c];
    float pd = acc * a_d[hh*16 + c];
    #pragma unroll
    for (int m = 1; m < 16; m <<= 1){ ps += __shfl_xor(ps, m); pd += __shfl_xor(pd, m); }
    if (valid && c == 0){ als[nc*HH + hh] = ps; ald[nc*HH + hh] = pd; }
}

// ---------------- CSR build ----------------

__global__ void zero_i32(int* __restrict__ p, int n){
    int i = blockIdx.x*256 + threadIdx.x;
    if (i < n) p[i] = 0;
}

__global__ void count_deg(const int* __restrict__ ei, int* __restrict__ deg, int E){
    int e = blockIdx.x*256 + threadIdx.x;
    if (e < E) atomicAdd(&deg[ei[E + e]], 1);
}

// multi-block scan, phase A: per-block (1024 vals) sums
__global__ void deg_bsum(const int* __restrict__ deg, int* __restrict__ bsum, int N){
    int t = threadIdx.x;
    int base = blockIdx.x*1024 + t*4;
    int s = 0;
    if (base + 3 < N){
        int4 v = *(const int4*)(deg + base);
        s = v.x + v.y + v.z + v.w;
    } else {
        for (int q = 0; q < 4; ++q) if (base + q < N) s += deg[base + q];
    }
    #pragma unroll
    for (int m = 1; m < 64; m <<= 1) s += __shfl_xor(s, m);
    __shared__ int ws[4];
    if ((t & 63) == 0) ws[t >> 6] = s;
    __syncthreads();
    if (t == 0) bsum[blockIdx.x] = ws[0] + ws[1] + ws[2] + ws[3];
}

// phase B: per-block exclusive scan + block offset (reduce preceding bsum in-kernel)
__global__ void scan_write(const int* __restrict__ deg, const int* __restrict__ bsum,
                           int* __restrict__ row_off, int* __restrict__ cursor, int N, int E){
    int t = threadIdx.x, bid = blockIdx.x, lane = t & 63, w = t >> 6;
    int base = bid*1024 + t*4;
    int v0 = 0, v1 = 0, v2 = 0, v3 = 0;
    if (base + 3 < N){
        int4 v = *(const int4*)(deg + base);
        v0 = v.x; v1 = v.y; v2 = v.z; v3 = v.w;
    } else {
        if (base     < N) v0 = deg[base];
        if (base + 1 < N) v1 = deg[base + 1];
        if (base + 2 < N) v2 = deg[base + 2];
        if (base + 3 < N) v3 = deg[base + 3];
    }
    int s = v0 + v1 + v2 + v3;
    int x = s;
    #pragma unroll
    for (int d = 1; d < 64; d <<= 1){
        int y = __shfl_up(x, d);
        if (lane >= d) x += y;
    }
    __shared__ int wsum[4];
    __shared__ int boff_s;
    if (lane == 63) wsum[w] = x;
    if (t < 64){
        int o = 0;
        for (int i = t; i < bid; i += 64) o += bsum[i];
        #pragma unroll
        for (int m = 1; m < 64; m <<= 1) o += __shfl_xor(o, m);
        if (t == 0) boff_s = o;
    }
    __syncthreads();
    int woff = 0;
    for (int i = 0; i < w; ++i) woff += wsum[i];
    int o = boff_s + woff + (x - s);
    if (base     < N){ row_off[base]     = o; cursor[base]     = o; o += v0; }
    if (base + 1 < N){ row_off[base + 1] = o; cursor[base + 1] = o; o += v1; }
    if (base + 2 < N){ row_off[base + 2] = o; cursor[base + 2] = o; o += v2; }
    if (base + 3 < N){ row_off[base + 3] = o; cursor[base + 3] = o; o += v3; }
    if (t == 0 && bid == 0) row_off[N] = E;
}

__global__ void fill_csr(const int* __restrict__ ei, int* __restrict__ cursor,
                         int* __restrict__ ssrc, int E){
    int e = blockIdx.x*256 + threadIdx.x;
    if (e < E){
        int d = ei[E + e];
        int p = atomicAdd(&cursor[d], 1);
        ssrc[p] = ei[e];
    }
}

// ---------------- layer-3 prep ----------------
__global__ void prep_l3(const float* __restrict__ W3, const float* __restrict__ a3s,
                        const float* __restrict__ a3d, float* __restrict__ ws3,
                        float* __restrict__ wd3, float* __restrict__ W3p){
    int t = threadIdx.x;          // 256 = (hh,k)
    int hh = t >> 6, k = t & 63;
    float ss = 0.f, sd = 0.f;
    for (int c = 0; c < 64; ++c){
        float w = W3[k*256 + hh*64 + c];
        ss += w * a3s[hh*64 + c];
        sd += w * a3d[hh*64 + c];
        W3p[t*64 + c] = 0.25f * w;
    }
    ws3[t] = ss; wd3[t] = sd;
}

// ---------------- fused segment-softmax + aggregate + bias + BN + ELU (concat layers) ----
// 4 nodes per 256-block, one wave per node. float4 gather: lane=(gq=lane>>4 edge-slot,
// cb=lane&15 channel-block). One dwordx4 load covers 4 edges' rows. Weight phase:
// lane (j=lane&15, hh=lane>>4) computes one (edge,head) weight into per-wave LDS table.
template<bool L3PREP>
__global__ void gat_agg16(const int* __restrict__ row_off, const int* __restrict__ ssrc,
                          const float* __restrict__ als, const float* __restrict__ ald,
                          const float* __restrict__ h, const float* __restrict__ b,
                          const float* __restrict__ g, const float* __restrict__ bb,
                          const float* __restrict__ bm, const float* __restrict__ bv,
                          float* __restrict__ out,
                          const float* __restrict__ ws3, const float* __restrict__ wd3,
                          float* __restrict__ als3, float* __restrict__ ald3, int N){
    int t = threadIdx.x, lane = t & 63, wid = t >> 6;
    int n = blockIdx.x*4 + wid;
    if (n >= N) return;   // no cross-wave LDS sharing; early return safe
    __shared__ float wl[4][16][4];   // [wave][edge][head]
    __shared__ int   sl[4][16];
    int j  = lane & 15;   // weight-phase edge slot
    int hh = lane >> 4;   // weight-phase head
    int cb = lane & 15;   // channel block (4 ch)
    int gq = lane >> 4;   // inner edge-group slot
    int hd = cb >> 2;     // head of my channels
    float ad_w = ald[n*HH + hh];
    float v_hd = __expf(lrelu(als[n*HH + hd] + ald[n*HH + hd]));
    int beg = row_off[n], end = row_off[n+1];
    float4 acc = make_float4(0.f, 0.f, 0.f, 0.f);
    if (lane < 16){
        float4 hs = *(const float4*)(h + (size_t)n*64 + cb*4);
        acc.x = v_hd*hs.x; acc.y = v_hd*hs.y; acc.z = v_hd*hs.z; acc.w = v_hd*hs.w;
    }
    float denp = 0.f;
    for (int c16 = beg; c16 < end; c16 += 16){
        int e = c16 + j;
        int s = n; float ev = 0.f;
        if (e < end){ s = ssrc[e]; ev = __expf(lrelu(als[s*HH + hh] + ad_w)); }
        denp += ev;
        wl[wid][j][hh] = ev;
        if (hh == 0) sl[wid][j] = s;
        int cnt = min(16, end - c16);
        for (int qb = 0; qb < cnt; qb += 8){
            int eA = qb + gq, eB = qb + 4 + gq;
            int   sA = sl[wid][eA],     sB = sl[wid][eB];
            float wA = wl[wid][eA][hd], wB = wl[wid][eB][hd];
            float4 hA = *(const float4*)(h + (size_t)sA*64 + cb*4);
            float4 hB = *(const float4*)(h + (size_t)sB*64 + cb*4);
            acc.x += wA*hA.x; acc.y += wA*hA.y; acc.z += wA*hA.z; acc.w += wA*hA.w;
            acc.x += wB*hB.x; acc.y += wB*hB.y; acc.z += wB*hB.z; acc.w += wB*hB.w;
        }
    }
    // den per head: reduce denp over edge-slot bits, then pull my head's value
    #pragma unroll
    for (int m = 1; m < 16; m <<= 1) denp += __shfl_xor(denp, m);
    float den = __shfl(denp, hd << 4) + v_hd;
    // combine the 4 edge-group partial accs (butterfly -> all lanes hold total)
    #pragma unroll
    for (int m = 16; m < 64; m <<= 1){
        acc.x += __shfl_xor(acc.x, m); acc.y += __shfl_xor(acc.y, m);
        acc.z += __shfl_xor(acc.z, m); acc.w += __shfl_xor(acc.w, m);
    }
    float4 bb4 = *(const float4*)(b  + cb*4);
    float4 gg4 = *(const float4*)(g  + cb*4);
    float4 be4 = *(const float4*)(bb + cb*4);
    float4 bm4 = *(const float4*)(bm + cb*4);
    float4 bv4 = *(const float4*)(bv + cb*4);
    float4 val;
    val.x = gg4.x*(acc.x/den + bb4.x - bm4.x)*rsqrtf(bv4.x + 1e-5f) + be4.x;
    val.y = gg4.y*(acc.y/den + bb4.y - bm4.y)*rsqrtf(bv4.y + 1e-5f) + be4.y;
    val.z = gg4.z*(acc.z/den + bb4.z - bm4.z)*rsqrtf(bv4.z + 1e-5f) + be4.z;
    val.w = gg4.w*(acc.w/den + bb4.w - bm4.w)*rsqrtf(bv4.w + 1e-5f) + be4.w;
    val.x = val.x > 0.f ? val.x : expm1f(val.x);
    val.y = val.y > 0.f ? val.y : expm1f(val.y);
    val.z = val.z > 0.f ? val.z : expm1f(val.z);
    val.w = val.w > 0.f ? val.w : expm1f(val.w);
    if (lane < 16) *(float4*)(out + (size_t)n*64 + cb*4) = val;
    if (L3PREP){
        // group gq computes layer-3 head jj=gq logits from the full row
        float4 w_s = *(const float4*)(ws3 + gq*64 + cb*4);
        float4 w_d = *(const float4*)(wd3 + gq*64 + cb*4);
        float ps = val.x*w_s.x + val.y*w_s.y + val.z*w_s.z + val.w*w_s.w;
        float pd = val.x*w_d.x + val.y*w_d.y + val.z*w_d.z + val.w*w_d.w;
        #pragma unroll
        for (int m = 1; m < 16; m <<= 1){ ps += __shfl_xor(ps, m); pd += __shfl_xor(pd, m); }
        if (cb == 0){ als3[n*HH + gq] = ps; ald3[n*HH + gq] = pd; }
    }
}

// ---------------- layer-3: aggregate hin (4 head-accs) + cooperative GEMM + BN -----------
// Aggregation: lane=(gq edge-slot, cb channel-block); float4 gathers cover 4 edges/instr;
// per-lane float4 acc per head. GEMM phase: wave w covers j-slice for all 4 nodes.
__global__ void gat_agg3_fused(const int* __restrict__ row_off, const int* __restrict__ ssrc,
                               const float* __restrict__ als, const float* __restrict__ ald,
                               const float* __restrict__ hin, const float* __restrict__ W3p,
                               const float* __restrict__ b, const float* __restrict__ g,
                               const float* __restrict__ bb, const float* __restrict__ bm,
                               const float* __restrict__ bv, float* __restrict__ out, int N){
    int t = threadIdx.x, lane = t & 63, wid = t >> 6;
    int n0 = blockIdx.x*4;
    int n = min(n0 + wid, N-1);          // clamp; no early return (syncthreads below)
    __shared__ __align__(16) float4 wlds[4][64];
    __shared__ int slds[4][64];
    __shared__ __align__(16) float ysh[4*256];
    __shared__ float red[4][4][64];      // [wave][node][lane]
    int cb = lane & 15, gq = lane >> 4;
    float4 adv = *(const float4*)(ald + n*4);
    float4 av  = *(const float4*)(als + n*4);
    float v0 = __expf(lrelu(av.x + adv.x)), v1 = __expf(lrelu(av.y + adv.y));
    float v2 = __expf(lrelu(av.z + adv.z)), v3 = __expf(lrelu(av.w + adv.w));
    int beg = row_off[n], end = row_off[n+1];
    float4 acc0 = make_float4(0,0,0,0), acc1 = acc0, acc2 = acc0, acc3 = acc0;
    if (lane < 16){
        float4 hs = *(const float4*)(hin + (size_t)n*64 + cb*4);
        acc0.x = v0*hs.x; acc0.y = v0*hs.y; acc0.z = v0*hs.z; acc0.w = v0*hs.w;
        acc1.x = v1*hs.x; acc1.y = v1*hs.y; acc1.z = v1*hs.z; acc1.w = v1*hs.w;
        acc2.x = v2*hs.x; acc2.y = v2*hs.y; acc2.z = v2*hs.z; acc2.w = v2*hs.w;
        acc3.x = v3*hs.x; acc3.y = v3*hs.y; acc3.z = v3*hs.z; acc3.w = v3*hs.w;
    }
    float dp0 = 0.f, dp1 = 0.f, dp2 = 0.f, dp3 = 0.f;
    for (int c64 = beg; c64 < end; c64 += 64){
        int e = c64 + lane;
        int s = n; float e0 = 0.f, e1 = 0.f, e2 = 0.f, e3 = 0.f;
        if (e < end){
            s = ssrc[e];
            float4 a = *(const float4*)(als + s*4);
            e0 = __expf(lrelu(a.x + adv.x));
            e1 = __expf(lrelu(a.y + adv.y));
            e2 = __expf(lrelu(a.z + adv.z));
            e3 = __expf(lrelu(a.w + adv.w));
        }
        dp0 += e0; dp1 += e1; dp2 += e2; dp3 += e3;
        wlds[wid][lane] = make_float4(e0, e1, e2, e3);   // same-wave produce/consume
        slds[wid][lane] = s;
        int cn = min(64, end - c64);
        for (int qb = 0; qb < cn; qb += 8){
            int eA = qb + gq, eB = qb + 4 + gq;
            int sA = slds[wid][eA], sB = slds[wid][eB];
            float4 wA = wlds[wid][eA], wB = wlds[wid][eB];
            float4 hA = *(const float4*)(hin + (size_t)sA*64 + cb*4);
            float4 hB = *(const float4*)(hin + (size_t)sB*64 + cb*4);
            acc0.x += wA.x*hA.x; acc0.y += wA.x*hA.y; acc0.z += wA.x*hA.z; acc0.w += wA.x*hA.w;
            acc1.x += wA.y*hA.x; acc1.y += wA.y*hA.y; acc1.z += wA.y*hA.z; acc1.w += wA.y*hA.w;
            acc2.x += wA.z*hA.x; acc2.y += wA.z*hA.y; acc2.z += wA.z*hA.z; acc2.w += wA.z*hA.w;
            acc3.x += wA.w*hA.x; acc3.y += wA.w*hA.y; acc3.z += wA.w*hA.z; acc3.w += wA.w*hA.w;
            acc0.x += wB.x*hB.x; acc0.y += wB.x*hB.y; acc0.z += wB.x*hB.z; acc0.w += wB.x*hB.w;
            acc1.x += wB.y*hB.x; acc1.y += wB.y*hB.y; acc1.z += wB.y*hB.z; acc1.w += wB.y*hB.w;
            acc2.x += wB.z*hB.x; acc2.y += wB.z*hB.y; acc2.z += wB.z*hB.z; acc2.w += wB.z*hB.w;
            acc3.x += wB.w*hB.x; acc3.y += wB.w*hB.y; acc3.z += wB.w*hB.z; acc3.w += wB.w*hB.w;
        }
    }
    #pragma unroll
    for (int m = 1; m < 64; m <<= 1){
        dp0 += __shfl_xor(dp0, m); dp1 += __shfl_xor(dp1, m);
        dp2 += __shfl_xor(dp2, m); dp3 += __shfl_xor(dp3, m);
    }
    // combine 4 edge-group partials (all lanes end with totals)
    #pragma unroll
    for (int m = 16; m < 64; m <<= 1){
        acc0.x += __shfl_xor(acc0.x, m); acc0.y += __shfl_xor(acc0.y, m);
        acc0.z += __shfl_xor(acc0.z, m); acc0.w += __shfl_xor(acc0.w, m);
        acc1.x += __shfl_xor(acc1.x, m); acc1.y += __shfl_xor(acc1.y, m);
        acc1.z += __shfl_xor(acc1.z, m); acc1.w += __shfl_xor(acc1.w, m);
        acc2.x += __shfl_xor(acc2.x, m); acc2.y += __shfl_xor(acc2.y, m);
        acc2.z += __shfl_xor(acc2.z, m); acc2.w += __shfl_xor(acc2.w, m);
        acc3.x += __shfl_xor(acc3.x, m); acc3.y += __shfl_xor(acc3.y, m);
        acc3.z += __shfl_xor(acc3.z, m); acc3.w += __shfl_xor(acc3.w, m);
    }
    if (lane < 16){
        float r0 = 1.f/(v0 + dp0), r1 = 1.f/(v1 + dp1);
        float r2 = 1.f/(v2 + dp2), r3 = 1.f/(v3 + dp3);
        float4 y0 = make_float4(acc0.x*r0, acc0.y*r0, acc0.z*r0, acc0.w*r0);
        float4 y1 = make_float4(acc1.x*r1, acc1.y*r1, acc1.z*r1, acc1.w*r1);
        float4 y2 = make_float4(acc2.x*r2, acc2.y*r2, acc2.z*r2, acc2.w*r2);
        float4 y3 = make_float4(acc3.x*r3, acc3.y*r3, acc3.z*r3, acc3.w*r3);
        *(float4*)&ysh[wid*256 +   0 + cb*4] = y0;
        *(float4*)&ysh[wid*256 +  64 + cb*4] = y1;
        *(float4*)&ysh[wid*256 + 128 + cb*4] = y2;
        *(float4*)&ysh[wid*256 + 192 + cb*4] = y3;
    }
    __syncthreads();
    // cooperative GEMM: wave wid covers j in [wid*64, wid*64+64) for all 4 nodes
    float a0 = 0.f, a1 = 0.f, a2 = 0.f, a3 = 0.f;
    int jbase = wid*64;
    #pragma unroll 4
    for (int jj = 0; jj < 64; jj += 4){
        int jb = jbase + jj;
        float4 y0 = *(const float4*)&ysh[0*256 + jb];
        float4 y1 = *(const float4*)&ysh[1*256 + jb];
        float4 y2 = *(const float4*)&ysh[2*256 + jb];
        float4 y3 = *(const float4*)&ysh[3*256 + jb];
        float w0 = W3p[(jb    )*64 + lane];
        float w1 = W3p[(jb + 1)*64 + lane];
        float w2 = W3p[(jb + 2)*64 + lane];
        float w3 = W3p[(jb + 3)*64 + lane];
        a0 += y0.x*w0 + y0.y*w1 + y0.z*w2 + y0.w*w3;
        a1 += y1.x*w0 + y1.y*w1 + y1.z*w2 + y1.w*w3;
        a2 += y2.x*w0 + y2.y*w1 + y2.z*w2 + y2.w*w3;
        a3 += y3.x*w0 + y3.y*w1 + y3.z*w2 + y3.w*w3;
    }
    red[wid][0][lane] = a0;
    red[wid][1][lane] = a1;
    red[wid][2][lane] = a2;
    red[wid][3][lane] = a3;
    __syncthreads();
    int nw = n0 + wid;
    if (nw < N){
        float val = red[0][wid][lane] + red[1][wid][lane] +
                    red[2][wid][lane] + red[3][wid][lane] + b[lane];
        out[(size_t)nw*64 + lane] = g[lane]*(val - bm[lane])*rsqrtf(bv[lane] + 1e-5f) + bb[lane];
    }
}

__global__ void classifier(const float* __restrict__ hin, const float* __restrict__ cW1,
                           const float* __restrict__ cb1, const float* __restrict__ cW2,
                           const float* __restrict__ cb2, float* __restrict__ out, int N){
    __shared__ float w1[64*32];
    __shared__ float b1s[32], w2[32];
    int t = threadIdx.x;
    for (int k = t; k < 64*32; k += 256) w1[k] = cW1[k];
    if (t < 32) { b1s[t] = cb1[t]; w2[t] = cW2[t]; }
    __syncthreads();
    int n = blockIdx.x*256 + t;
    if (n >= N) return;
    float hrow[64];
    #pragma unroll
    for (int k = 0; k < 64; ++k) hrow[k] = hin[(size_t)n*64 + k];
    float acc2 = cb2[0];
    #pragma unroll 4
    for (int j = 0; j < 32; ++j) {
        float a = b1s[j];
        #pragma unroll
        for (int k = 0; k < 64; ++k) a += hrow[k]*w1[k*32 + j];
        float e = a > 0.f ? a : expm1f(a);
        acc2 += e * w2[j];
    }
    out[n] = acc2;
}

extern "C" void kernel_launch(void* const* d_in, const int* in_sizes, int n_in,
                              void* d_out, int out_size, void* d_ws, size_t ws_size,
                              hipStream_t stream) {
    const float* x    = (const float*)d_in[0];
    const int*   ei   = (const int*)  d_in[1];
    const float* W1   = (const float*)d_in[2];
    const float* a1s  = (const float*)d_in[3];
    const float* a1d  = (const float*)d_in[4];
    const float* b1   = (const float*)d_in[5];
    const float* W2   = (const float*)d_in[6];
    const float* a2s  = (const float*)d_in[7];
    const float* a2d  = (const float*)d_in[8];
    const float* b2   = (const float*)d_in[9];
    const float* W3   = (const float*)d_in[10];
    const float* a3s  = (const float*)d_in[11];
    const float* a3d  = (const float*)d_in[12];
    const float* b3   = (const float*)d_in[13];
    const float* bn1g = (const float*)d_in[14];
    const float* bn1b = (const float*)d_in[15];
    const float* bn1m = (const float*)d_in[16];
    const float* bn1v = (const float*)d_in[17];
    const float* bn2g = (const float*)d_in[18];
    const float* bn2b = (const float*)d_in[19];
    const float* bn2m = (const float*)d_in[20];
    const float* bn2v = (const float*)d_in[21];
    const float* bn3g = (const float*)d_in[22];
    const float* bn3b = (const float*)d_in[23];
    const float* bn3m = (const float*)d_in[24];
    const float* bn3v = (const float*)d_in[25];
    const float* cW1  = (const float*)d_in[26];
    const float* cb1  = (const float*)d_in[27];
    const float* cW2  = (const float*)d_in[28];
    const float* cb2  = (const float*)d_in[29];

    const int N = in_sizes[0] / 128;
    const int E = in_sizes[1] / 2;

    // ws layout (floats): h[64N] hin[64N] als[4N] ald[4N] als3[4N] ald3[4N]
    //                     ws3[256] wd3[256] W3p[16384]
    // ints: deg[N] row_off[N+1] cursor[N] ssrc[E] bsum[NB]
    float* h    = (float*)d_ws;
    float* hin  = h    + (size_t)N*64;
    float* als  = hin  + (size_t)N*64;
    float* ald  = als  + (size_t)N*4;
    float* als3 = ald  + (size_t)N*4;
    float* ald3 = als3 + (size_t)N*4;
    float* ws3  = ald3 + (size_t)N*4;
    float* wd3  = ws3  + 256;
    float* W3p  = wd3  + 256;
    int* deg     = (int*)(W3p + 16384);
    int* row_off = deg + N;
    int* cursor  = row_off + (N + 1);
    int* ssrc    = cursor + N;
    int* bsum    = ssrc + E;

    const int B = 256;
    int gN  = (N + B-1)/B;
    int gE  = (E + B-1)/B;
    int NB  = (N + 1023)/1024;
    int gN4 = (N + 3)/4;

    // ---- CSR build (dst-grouped src lists), reused by all 3 layers ----
    zero_i32<<<gN, B, 0, stream>>>(deg, N);
    count_deg<<<gE, B, 0, stream>>>(ei, deg, E);
    deg_bsum<<<NB, B, 0, stream>>>(deg, bsum, N);
    scan_write<<<NB, B, 0, stream>>>(deg, bsum, row_off, cursor, N, E);
    fill_csr<<<gE, B, 0, stream>>>(ei, cursor, ssrc, E);
    prep_l3<<<1, 256, 0, stream>>>(W3, a3s, a3d, ws3, wd3, W3p);

    // ---- layer 1 (IC=128, C=16, concat) ----
    gemm_gat<128><<<gN4, B, 0, stream>>>(x, W1, a1s, a1d, h, als, ald, N);
    gat_agg16<false><<<gN4, B, 0, stream>>>(row_off, ssrc, als, ald, h, b1,
                                            bn1g, bn1b, bn1m, bn1v, hin,
                                            nullptr, nullptr, nullptr, nullptr, N);

    // ---- layer 2 (IC=64, C=16, concat) + layer-3 logits in epilogue ----
    gemm_gat<64><<<gN4, B, 0, stream>>>(hin, W2, a2s, a2d, h, als, ald, N);
    gat_agg16<true><<<gN4, B, 0, stream>>>(row_off, ssrc, als, ald, h, b2,
                                           bn2g, bn2b, bn2m, bn2v, hin,
                                           ws3, wd3, als3, ald3, N);

    // ---- layer 3: aggregate hin + cooperative per-block GEMM + mean + BN ----
    gat_agg3_fused<<<gN4, B, 0, stream>>>(row_off, ssrc, als3, ald3, hin, W3p,
                                          b3, bn3g, bn3b, bn3m, bn3v, h, N);

    // ---- classifier ----
    classifier<<<gN, B, 0, stream>>>(h, cW1, cb1, cW2, cb2, (float*)d_out, N);
}